// Round 2
// 376.952 us; speedup vs baseline: 1.0263x; 1.0263x over previous
//
#include <hip/hip_runtime.h>
#include <hip/hip_bf16.h>

// Problem constants (reference: D=128, BC=64, BS=512, K=6, OV=128, B=8)
#define NB 8            // batches
#define LSEQ 32768      // BC*BS positions per batch
#define DCH 128         // channels
#define NCHUNK 1024     // 256-row chunks
#define NSUB 4096       // 64-row sub-chunks
#define NBLK 512        // B*BC conv blocks
#define PH 520          // padded rows per block (2 front + 512 + pad, rounded)
#define SCALE_F 0.08838834764831845f

typedef __bf16 bf16x8 __attribute__((ext_vector_type(8)));
typedef float f32x4 __attribute__((ext_vector_type(4)));

__device__ __forceinline__ float bf2f(unsigned short u) {
    return __uint_as_float(((unsigned)u) << 16);
}
__device__ __forceinline__ unsigned short f2bf(float f) {
    unsigned u = __float_as_uint(f);
    u += 0x7fffu + ((u >> 16) & 1u);   // round-to-nearest-even
    return (unsigned short)(u >> 16);
}

// async global->LDS DMA, 16 B per lane; LDS dest = wave-uniform base + lane*16
__device__ __forceinline__ void async_copy16(const void* gsrc, void* ldst) {
    __builtin_amdgcn_global_load_lds(
        (const __attribute__((address_space(1))) unsigned int*)gsrc,
        (__attribute__((address_space(3))) unsigned int*)ldst, 16, 0, 0);
}

// ---------------- Stage 1: logits = silu(x @ w_lw + b); per-64-row-sub max ----------------
// Column-parallel dot (LDS partials), no per-row shuffle trees.
// NOTE (R5/R6 post-mortem): reference weights are w_i = exp(l_i - cummax_i) —
// frozen at insertion, never rescaled. The cummax does NOT cancel. Keep it.
__global__ __launch_bounds__(256) void k_logits2(const float* __restrict__ x,
                                                 const float* __restrict__ w_lw,
                                                 const float* __restrict__ b_lw,
                                                 float* __restrict__ logits,
                                                 float* __restrict__ subM) {
    int chunk = blockIdx.x, t = threadIdx.x;
    int g = t & 15, rs = t >> 4;
    __shared__ float sp[256 * 17];
    __shared__ float red[256];
    float wv[8];
    #pragma unroll
    for (int e = 0; e < 8; ++e) wv[e] = w_lw[g * 8 + e];
    float bb = b_lw[0];
    size_t base = (size_t)chunk * 256 * DCH;
    for (int i = 0; i < 16; ++i) {
        int row = rs * 16 + i;
        float4 a  = *(const float4*)(x + base + (size_t)row * DCH + g * 8);
        float4 b4 = *(const float4*)(x + base + (size_t)row * DCH + g * 8 + 4);
        sp[row * 17 + g] = a.x * wv[0] + a.y * wv[1] + a.z * wv[2] + a.w * wv[3] +
                           b4.x * wv[4] + b4.y * wv[5] + b4.z * wv[6] + b4.w * wv[7];
    }
    __syncthreads();
    float s = bb;
    #pragma unroll
    for (int j = 0; j < 16; ++j) s += sp[t * 17 + j];
    float l = s / (1.f + expf(-s));          // silu
    logits[(size_t)chunk * 256 + t] = l;
    red[t] = l;
    __syncthreads();
    for (int off = 32; off >= 1; off >>= 1) {
        if ((t & 63) < off) red[t] = fmaxf(red[t], red[t + off]);
        __syncthreads();
    }
    if ((t & 63) == 0) subM[chunk * 4 + (t >> 6)] = red[t];
}

// ---------------- Stage 2: exclusive prefix-MAX over 512 subs per batch ----------------
// 3-phase wave scan: lane owns 8 subs; shfl_up inclusive scan; rewalk.
__global__ __launch_bounds__(64) void k_seed_max2(const float* __restrict__ subM,
                                                  float* __restrict__ seedM) {
    int b = blockIdx.x, lane = threadIdx.x;
    const float* src = subM + b * 512;
    float* dst = seedM + b * 512;
    float v[8];
    float m = -INFINITY;
    #pragma unroll
    for (int j = 0; j < 8; ++j) { v[j] = src[lane * 8 + j]; m = fmaxf(m, v[j]); }
    float incl = m;
    #pragma unroll
    for (int off = 1; off < 64; off <<= 1) {
        float o = __shfl_up(incl, off, 64);
        if (lane >= off) incl = fmaxf(incl, o);
    }
    float ex = __shfl_up(incl, 1, 64);
    if (lane == 0) ex = -INFINITY;
    float run = ex;
    #pragma unroll
    for (int j = 0; j < 8; ++j) { dst[lane * 8 + j] = run; run = fmaxf(run, v[j]); }
}

// ---------------- Stage 3: w_i = exp(l_i - max(seedM, cummax_loc)); sub sums ----------------
__global__ __launch_bounds__(256) void k_sums(const float* __restrict__ x,
                                              const float* __restrict__ logits,
                                              const float* __restrict__ seedM,
                                              float* __restrict__ exg,
                                              float* __restrict__ S_w,
                                              float* __restrict__ S_wx) {
    int chunk = blockIdx.x, t = threadIdx.x;
    int g = t & 15, rs = t >> 4;
    __shared__ float llog[256];
    __shared__ float wbuf[256];
    __shared__ float red[256];
    __shared__ float rp[16 * 130];
    llog[t] = logits[(size_t)chunk * 256 + t];
    __syncthreads();
    if (t < 4) {                                // serial 64-deep running max per sub
        float M = seedM[chunk * 4 + t];
        float m = -INFINITY;
        for (int i = 0; i < 64; ++i) {
            float l = llog[t * 64 + i];
            m = fmaxf(m, l);
            wbuf[t * 64 + i] = expf(l - fmaxf(M, m));
        }
    }
    __syncthreads();
    float w_t = wbuf[t];
    exg[(size_t)chunk * 256 + t] = w_t;
    red[t] = w_t;
    __syncthreads();
    for (int off = 32; off >= 1; off >>= 1) {
        if ((t & 63) < off) red[t] += red[t + off];
        __syncthreads();
    }
    if ((t & 63) == 0) S_w[chunk * 4 + (t >> 6)] = red[t];
    // column-parallel S_wx: thread (g,rs) covers rows rs*16..+15 (all in sub rs>>2)
    float acc[8];
    #pragma unroll
    for (int e = 0; e < 8; ++e) acc[e] = 0.f;
    size_t base = (size_t)chunk * 256 * DCH;
    for (int i = 0; i < 16; ++i) {
        int row = rs * 16 + i;
        float w = wbuf[row];
        float4 a  = *(const float4*)(x + base + (size_t)row * DCH + g * 8);
        float4 b4 = *(const float4*)(x + base + (size_t)row * DCH + g * 8 + 4);
        acc[0] += w * a.x;  acc[1] += w * a.y;  acc[2] += w * a.z;  acc[3] += w * a.w;
        acc[4] += w * b4.x; acc[5] += w * b4.y; acc[6] += w * b4.z; acc[7] += w * b4.w;
    }
    #pragma unroll
    for (int e = 0; e < 8; ++e) rp[rs * 130 + g * 8 + e] = acc[e];
    __syncthreads();
    #pragma unroll
    for (int k = 0; k < 2; ++k) {
        int idx = k * 256 + t;                 // 4 subs x 128 ch
        int sub = idx >> 7, c = idx & 127;
        float sm = rp[(sub * 4 + 0) * 130 + c] + rp[(sub * 4 + 1) * 130 + c] +
                   rp[(sub * 4 + 2) * 130 + c] + rp[(sub * 4 + 3) * 130 + c];
        S_wx[((size_t)chunk * 4 + sub) * DCH + c] = sm;
    }
}

// ---------------- Stage 4a: exclusive prefix-SUM of S_w (512/batch), wave scan ----------------
__global__ __launch_bounds__(64) void k_seed_w(const float* __restrict__ S_w,
                                               float* __restrict__ sS_w) {
    int b = blockIdx.x, lane = threadIdx.x;
    const float* src = S_w + b * 512;
    float* dst = sS_w + b * 512;
    float v[8];
    float tot = 0.f;
    #pragma unroll
    for (int j = 0; j < 8; ++j) { v[j] = src[lane * 8 + j]; tot += v[j]; }
    float incl = tot;
    #pragma unroll
    for (int off = 1; off < 64; off <<= 1) {
        float o = __shfl_up(incl, off, 64);
        if (lane >= off) incl += o;
    }
    float ex = __shfl_up(incl, 1, 64);
    if (lane == 0) ex = 0.f;
    float run = ex;
    #pragma unroll
    for (int j = 0; j < 8; ++j) { dst[lane * 8 + j] = run; run += v[j]; }
}

// ---------------- Stage 4b: exclusive prefix-SUM of S_wx per channel, 3-phase ----------------
// block = (batch, 16-channel group); thread = (segment of 32 subs, channel)
__global__ __launch_bounds__(256) void k_seed_sums2(const float* __restrict__ S_wx,
                                                    float* __restrict__ sS_wx) {
    int b = blockIdx.x >> 3, cg = blockIdx.x & 7;
    int t = threadIdx.x;
    int cl = t & 15, seg = t >> 4;
    int c = cg * 16 + cl;
    __shared__ float tots[16][17];
    const float* src = S_wx + (size_t)b * 512 * DCH + c;
    float* dst = sS_wx + (size_t)b * 512 * DCH + c;
    int s0 = seg * 32;
    float tot = 0.f;
    for (int j = 0; j < 32; ++j) tot += src[(size_t)(s0 + j) * DCH];
    tots[seg][cl] = tot;
    __syncthreads();
    if (t < 16) {
        float run = 0.f;
        for (int s = 0; s < 16; ++s) { float tmp = tots[s][t]; tots[s][t] = run; run += tmp; }
    }
    __syncthreads();
    float run = tots[seg][cl];
    for (int j = 0; j < 32; ++j) {
        float val = src[(size_t)(s0 + j) * DCH];
        dst[(size_t)(s0 + j) * DCH] = run;
        run += val;
    }
}

// ---------------- zero the halo rows of P ----------------
__global__ __launch_bounds__(256) void k_zero_pad(unsigned short* __restrict__ P) {
    int n = blockIdx.x, t = threadIdx.x;
    for (int i = t; i < 1024; i += 256) {
        int rr = i >> 7;                       // 0..7
        int row = (rr < 2) ? rr : 512 + rr;    // rows 0,1,514..519
        P[(n * PH + row) * DCH + (i & 127)] = 0;
    }
}

// ---------------- Stage 5: apply scan -> prefix_x, write bf16 padded P ----------------
// One wave per 64-row sub-chunk; lane owns a channel pair; fp32 x input.
__global__ __launch_bounds__(128) void k_apply(const float* __restrict__ x,
                                               const float* __restrict__ exg,
                                               const float* __restrict__ sS_w,
                                               const float* __restrict__ sS_wx,
                                               unsigned short* __restrict__ P) {
    int t = threadIdx.x, w = t >> 6, lane = t & 63;
    int s = blockIdx.x * 2 + w;                // sub-chunk id
    int b = s >> 9, sb = s & 511;
    __shared__ float e2[128];
    e2[t] = exg[(size_t)blockIdx.x * 128 + t]; // both waves' w values
    float2 axx = *(const float2*)(sS_wx + (size_t)s * DCH + 2 * lane);
    float aex = sS_w[s];
    __syncthreads();
    const float* es = e2 + w * 64;
    int pib0 = sb * 64;
    int n = b * 64 + (pib0 >> 9);
    int row0 = (pib0 & 511) + 2;
    const float* xp = x + ((size_t)b * LSEQ + pib0) * DCH + 2 * lane;
    unsigned short* pp = P + ((size_t)n * PH + row0) * DCH + 2 * lane;
    for (int j = 0; j < 64; ++j) {
        float e = es[j];
        aex += e;
        float2 xv = *(const float2*)xp;
        axx.x += e * xv.x;
        axx.y += e * xv.y;
        float inv = 1.f / aex;
        unsigned pk = ((unsigned)f2bf(axx.y * inv + xv.y) << 16) | f2bf(axx.x * inv + xv.x);
        *(unsigned*)pp = pk;
        xp += DCH;
        pp += DCH;
    }
}

// ---------------- weight repack: fragment-ordered B for direct reg loads ----------------
// W3 flat index f = (((kt*2+ks)*4 + kchunk)*128 + o)*8 + e
//   maps to conv_w[o][ i ][ kn ],  i = (kt&1)*64 + (ks*4+kchunk)*8 + e,  kn = kt>>1.
// A wave's B-fragment load (fixed kt,ks,ni) is then 4 x 256 B coalesced segments.
__global__ __launch_bounds__(256) void k_w2t(const float* __restrict__ conv_w,
                                             unsigned short* __restrict__ W3) {
    int idx = blockIdx.x * 256 + threadIdx.x;  // 24*4*128*8 = 98304
    if (idx < 98304) {
        int e  = idx & 7;
        int o  = (idx >> 3) & 127;
        int kc = (idx >> 10) & 3;
        int kt2 = idx >> 12;                   // 0..23 = kt*2+ks
        int kt = kt2 >> 1, ks = kt2 & 1;
        int i  = (kt & 1) * 64 + (ks * 4 + kc) * 8 + e;
        int kn = kt >> 1;
        W3[idx] = f2bf(conv_w[(o * 128 + i) * 6 + kn]);
    }
}

// ---------------- Stage 6: conv as bf16 MFMA GEMM (128x128 tile, K=768) ----------------
// v2: A-tile double-buffered in LDS (2 x 16 KB) with ONE barrier per K-step
// (T3 minimum 2-phase: DMA for kt+1 issued before compute of kt; the single
// __syncthreads() drains vmcnt AND protects buffer reuse). B operands no longer go
// through LDS at all: W3 is 192 KB, shared by all 2048 workgroups -> L2-resident;
// fragments are loaded straight into registers (double-buffered, static indices via
// full unroll). LDS traffic per block-K-step drops 96 KB -> 48 KB, below the
// MFMA time, and staging now overlaps compute.
__global__ __launch_bounds__(256) void k_conv(const unsigned short* __restrict__ P,
                                              const unsigned short* __restrict__ W3,
                                              const float* __restrict__ conv_b,
                                              unsigned short* __restrict__ convout) {
    int n = blockIdx.x >> 2;
    int h0 = (blockIdx.x & 3) * 128;
    __shared__ __align__(16) unsigned short lds[128 * 136];  // 34816 B; loop uses first 32 KB as A dbuf
    char* abuf0 = (char*)lds;
    char* abuf1 = (char*)lds + 16384;
    int t = threadIdx.x;
    int wave = t >> 6, lane = t & 63;
    f32x4 acc[4][4] = {};
    const unsigned short* Pn = P + (size_t)n * PH * DCH;
    int wm = (wave >> 1) * 64, wn = (wave & 1) * 64;
    int cpos = lane & 7;                      // LDS chunk position this lane fills (DMA)
    int kchunk = lane >> 4;                   // 0..3 (MFMA k-slice group)
    int bcol = wn + (lane & 15);              // B out-channel base (+ni*16)

    bf16x8 breg[2][8];

    auto stageA = [&](int kt, char* dst) {
        int kn = kt >> 1, c0 = (kt & 1) * 64;
        #pragma unroll
        for (int j = 0; j < 4; ++j) {
            int r = (wave * 4 + j) * 8 + (lane >> 3);   // LDS row 0..127
            int gr = h0 + kn + r;                       // global padded row
            int csrcA = cpos ^ (gr & 7);                // source-side swizzle
            async_copy16(Pn + (size_t)gr * DCH + c0 + csrcA * 8,
                         dst + (wave * 4 + j) * 1024 + lane * 16);
        }
    };
    auto loadB = [&](int kt, bf16x8* dstB) {
        #pragma unroll
        for (int ks = 0; ks < 2; ++ks)
            #pragma unroll
            for (int ni = 0; ni < 4; ++ni)
                dstB[ks * 4 + ni] = *(const bf16x8*)(
                    W3 + (size_t)((kt * 2 + ks) * 4 + kchunk) * 1024 + (bcol + ni * 16) * 8);
    };

    // prologue: stage kt=0 (A via DMA, B via L2->reg)
    stageA(0, abuf0);
    loadB(0, breg[0]);
    __syncthreads();                           // drains vmcnt(0): buf0 + breg[0] ready

    #pragma unroll
    for (int kt = 0; kt < 12; ++kt) {
        char* cbuf = (kt & 1) ? abuf1 : abuf0;
        if (kt < 11) {
            stageA(kt + 1, (kt & 1) ? abuf0 : abuf1);  // DMA next tile into other buffer
            loadB(kt + 1, breg[(kt + 1) & 1]);         // prefetch next B frags from L2
        }
        int kn = kt >> 1;
        #pragma unroll
        for (int ks = 0; ks < 2; ++ks) {
            bf16x8 af[4];
            #pragma unroll
            for (int mi = 0; mi < 4; ++mi) {
                int rA = wm + mi * 16 + (lane & 15);
                int pA = (ks * 4 + kchunk) ^ ((kn + rA) & 7);
                af[mi] = *(const bf16x8*)(cbuf + rA * 128 + pA * 16);
            }
            #pragma unroll
            for (int mi = 0; mi < 4; ++mi)
                #pragma unroll
                for (int ni = 0; ni < 4; ++ni)
                    acc[mi][ni] = __builtin_amdgcn_mfma_f32_16x16x32_bf16(af[mi],
                                                                          breg[kt & 1][ks * 4 + ni],
                                                                          acc[mi][ni], 0, 0, 0);
        }
        __syncthreads();   // publishes buf[kt+1] (vmcnt) + all reads of buf[kt] done
    }
    // C/D layout: col=lane&15, row=(lane>>4)*4+reg  [m89-verified]
    #pragma unroll
    for (int mi = 0; mi < 4; ++mi)
        #pragma unroll
        for (int ni = 0; ni < 4; ++ni) {
            int col = wn + ni * 16 + (lane & 15);
            float bias = conv_b[col];
            #pragma unroll
            for (int r = 0; r < 4; ++r) {
                int row = wm + mi * 16 + (lane >> 4) * 4 + r;
                lds[row * 136 + col] = f2bf(acc[mi][ni][r] + bias);
            }
        }
    __syncthreads();
    // coalesced store: 2048 granules of 16 B
    size_t base = (size_t)(n * 512 + h0) * DCH;
    #pragma unroll
    for (int it = 0; it < 8; ++it) {
        int idx = it * 256 + t;
        int row = idx >> 4, g = idx & 15;
        uint4 v = *(const uint4*)(lds + row * 136 + g * 8);
        *(uint4*)(convout + base + (size_t)row * DCH + g * 8) = v;
    }
}

// ---------------- Stage 7 fused: block_repr + a_s, column-parallel uint4 passes ----------------
__global__ __launch_bounds__(256) void k_as(const unsigned short* __restrict__ conv,
                                            float* __restrict__ block_repr,
                                            float* __restrict__ a_s) {
    int n = blockIdx.x, t = threadIdx.x;
    int g = t & 15, rs = t >> 4;
    __shared__ __align__(16) float sp[512 * 17];   // row-partials / rp[16][130] / red scratch
    __shared__ float s[512];
    __shared__ float br[128];
    float* rp = sp;                                 // [16][130] view
    const unsigned short* base = conv + (size_t)n * 512 * DCH;

    // ---- phase 0: column max ----
    float m[8];
    #pragma unroll
    for (int e = 0; e < 8; ++e) m[e] = -INFINITY;
    for (int i = 0; i < 32; ++i) {
        int row = i * 16 + rs;
        uint4 v = *(const uint4*)(base + row * DCH + g * 8);
        unsigned vv[4] = {v.x, v.y, v.z, v.w};
        #pragma unroll
        for (int e = 0; e < 4; ++e) {
            m[2 * e]     = fmaxf(m[2 * e],     bf2f((unsigned short)(vv[e] & 0xffff)));
            m[2 * e + 1] = fmaxf(m[2 * e + 1], bf2f((unsigned short)(vv[e] >> 16)));
        }
    }
    #pragma unroll
    for (int e = 0; e < 8; ++e) rp[rs * 130 + g * 8 + e] = m[e];
    __syncthreads();
    if (t < 128) {
        float bm = rp[t];
        #pragma unroll
        for (int r2 = 1; r2 < 16; ++r2) bm = fmaxf(bm, rp[r2 * 130 + t]);
        br[t] = bm;
        block_repr[n * DCH + t] = bm;
    }
    __syncthreads();

    // ---- phase 1: scores s[row] = (conv[row] . br) * SCALE ----
    float brv[8];
    #pragma unroll
    for (int e = 0; e < 8; ++e) brv[e] = br[g * 8 + e];
    for (int i = 0; i < 32; ++i) {
        int row = i * 16 + rs;
        uint4 v = *(const uint4*)(base + row * DCH + g * 8);
        unsigned vv[4] = {v.x, v.y, v.z, v.w};
        float p = 0.f;
        #pragma unroll
        for (int e = 0; e < 4; ++e) {
            p += bf2f((unsigned short)(vv[e] & 0xffff)) * brv[2 * e];
            p += bf2f((unsigned short)(vv[e] >> 16))    * brv[2 * e + 1];
        }
        sp[row * 17 + g] = p;
    }
    __syncthreads();
    #pragma unroll
    for (int rr = 0; rr < 2; ++rr) {
        int row = t * 2 + rr;
        float p = 0.f;
        #pragma unroll
        for (int j = 0; j < 16; ++j) p += sp[row * 17 + j];
        s[row] = p * SCALE_F;
    }
    __syncthreads();

    // ---- softmax over s[512] (scratch reuses sp after scores consumed) ----
    float* red = sp;
    float mm = fmaxf(s[t], s[t + 256]);
    __syncthreads();          // all score reads of sp done before overwrite
    red[t] = mm;
    __syncthreads();
    for (int off = 128; off > 0; off >>= 1) {
        if (t < off) red[t] = fmaxf(red[t], red[t + off]);
        __syncthreads();
    }
    float smax = red[0];
    __syncthreads();
    float e0 = expf(s[t] - smax), e1 = expf(s[t + 256] - smax);
    red[t] = e0 + e1;
    __syncthreads();
    for (int off = 128; off > 0; off >>= 1) {
        if (t < off) red[t] += red[t + off];
        __syncthreads();
    }
    float inv = 1.f / red[0];
    __syncthreads();
    s[t] = e0 * inv;
    s[t + 256] = e1 * inv;
    __syncthreads();

    // ---- phase 2: weighted sum ----
    float acc[8];
    #pragma unroll
    for (int e = 0; e < 8; ++e) acc[e] = 0.f;
    for (int i = 0; i < 32; ++i) {
        int row = i * 16 + rs;
        float w = s[row];
        uint4 v = *(const uint4*)(base + row * DCH + g * 8);
        unsigned vv[4] = {v.x, v.y, v.z, v.w};
        #pragma unroll
        for (int e = 0; e < 4; ++e) {
            acc[2 * e]     += w * bf2f((unsigned short)(vv[e] & 0xffff));
            acc[2 * e + 1] += w * bf2f((unsigned short)(vv[e] >> 16));
        }
    }
    #pragma unroll
    for (int e = 0; e < 8; ++e) rp[rs * 130 + g * 8 + e] = acc[e];
    __syncthreads();
    if (t < 128) {
        float p = 0.f;
        #pragma unroll
        for (int r2 = 0; r2 < 16; ++r2) p += rp[r2 * 130 + t];
        a_s[n * DCH + t] = p;
    }
}

// ---------------- Stage 8: a_o = attn(block_repr, xbo, xbo), column-parallel ----------------
__global__ __launch_bounds__(256) void k_ao(const unsigned short* __restrict__ P,
                                            const float* __restrict__ block_repr,
                                            float* __restrict__ a_o) {
    int n = blockIdx.x, t = threadIdx.x;
    int g = t & 15, rs = t >> 4;
    int b = n >> 6, c = n & 63;
    __shared__ float br[128];
    __shared__ int rb[128];
    __shared__ __align__(16) float sp[128 * 17];   // scores partials / rp[16][130]
    __shared__ float s[128];
    __shared__ float red[128];
    if (t < 128) {
        br[t] = block_repr[n * DCH + t];
        int pib = (c + 1) * 512 - 64 + t;       // window straddling block end
        pib = min(pib, LSEQ - 1);               // edge-clamp at sequence end
        int n2 = b * 64 + (pib >> 9);
        int row = (pib & 511) + 2;
        rb[t] = (n2 * PH + row) * DCH;
    }
    __syncthreads();
    float brv[8];
    #pragma unroll
    for (int e = 0; e < 8; ++e) brv[e] = br[g * 8 + e];
    #pragma unroll
    for (int r = 0; r < 8; ++r) {
        int row = rs * 8 + r;
        uint4 v = *(const uint4*)(P + rb[row] + g * 8);
        unsigned vv[4] = {v.x, v.y, v.z, v.w};
        float p = 0.f;
        #pragma unroll
        for (int e = 0; e < 4; ++e) {
            p += bf2f((unsigned short)(vv[e] & 0xffff)) * brv[2 * e];
            p += bf2f((unsigned short)(vv[e] >> 16))    * brv[2 * e + 1];
        }
        sp[row * 17 + g] = p;
    }
    __syncthreads();
    if (t < 128) {
        float p = 0.f;
        #pragma unroll
        for (int j = 0; j < 16; ++j) p += sp[t * 17 + j];
        s[t] = p * SCALE_F;
        red[t] = s[t];
    }
    __syncthreads();
    for (int off = 64; off > 0; off >>= 1) {
        if (t < off) red[t] = fmaxf(red[t], red[t + off]);
        __syncthreads();
    }
    float smax = red[0];
    __syncthreads();
    if (t < 128) {
        float e = expf(s[t] - smax);
        s[t] = e;
        red[t] = e;
    }
    __syncthreads();
    for (int off = 64; off > 0; off >>= 1) {
        if (t < off) red[t] += red[t + off];
        __syncthreads();
    }
    float inv = 1.f / red[0];
    __syncthreads();
    if (t < 128) s[t] *= inv;
    __syncthreads();
    float acc[8];
    #pragma unroll
    for (int e = 0; e < 8; ++e) acc[e] = 0.f;
    #pragma unroll
    for (int r = 0; r < 8; ++r) {
        int row = rs * 8 + r;
        float w = s[row];
        uint4 v = *(const uint4*)(P + rb[row] + g * 8);
        unsigned vv[4] = {v.x, v.y, v.z, v.w};
        #pragma unroll
        for (int e = 0; e < 4; ++e) {
            acc[2 * e]     += w * bf2f((unsigned short)(vv[e] & 0xffff));
            acc[2 * e + 1] += w * bf2f((unsigned short)(vv[e] >> 16));
        }
    }
    #pragma unroll
    for (int e = 0; e < 8; ++e) sp[rs * 130 + g * 8 + e] = acc[e];
    __syncthreads();
    if (t < 128) {
        float p = 0.f;
        #pragma unroll
        for (int r2 = 0; r2 < 16; ++r2) p += sp[r2 * 130 + t];
        a_o[n * DCH + t] = p;
    }
}

// ---------------- Stage 9: out = concat(a_s,a_o,br) @ fusion_w + fusion_b (x2 copies) ----------------
__global__ __launch_bounds__(128) void k_fusion(const float* __restrict__ a_s,
                                                const float* __restrict__ a_o,
                                                const float* __restrict__ block_repr,
                                                const float* __restrict__ fusion_w,
                                                const float* __restrict__ fusion_b,
                                                float* __restrict__ out) {
    int n = blockIdx.x, t = threadIdx.x;
    __shared__ float fu[384];
    fu[t] = a_s[n * DCH + t];
    fu[128 + t] = a_o[n * DCH + t];
    fu[256 + t] = block_repr[n * DCH + t];
    __syncthreads();
    float acc = fusion_b[t];
    for (int j = 0; j < 384; j++) acc += fu[j] * fusion_w[j * DCH + t];
    out[n * DCH + t] = acc;
    out[NB * 64 * DCH + n * DCH + t] = acc;   // second tuple element (out, out)
}

extern "C" void kernel_launch(void* const* d_in, const int* in_sizes, int n_in,
                              void* d_out, int out_size, void* d_ws, size_t ws_size,
                              hipStream_t stream) {
    const float* x        = (const float*)d_in[0];
    const float* w_lw     = (const float*)d_in[1];
    const float* b_lw     = (const float*)d_in[2];
    const float* conv_w   = (const float*)d_in[3];
    const float* conv_b   = (const float*)d_in[4];
    const float* fusion_w = (const float*)d_in[5];
    const float* fusion_b = (const float*)d_in[6];
    float* out = (float*)d_out;

    char* ws = (char*)d_ws;
    size_t off = 0;
    auto alloc = [&](size_t bytes) { char* p = ws + off; off += (bytes + 255) & ~(size_t)255; return p; };
    float* logits     = (float*)alloc(NB * LSEQ * 4);
    float* exg        = (float*)alloc(NB * LSEQ * 4);
    float* subM       = (float*)alloc(NSUB * 4);
    float* seedM      = (float*)alloc(NSUB * 4);
    float* S_w        = (float*)alloc(NSUB * 4);
    float* sS_w       = (float*)alloc(NSUB * 4);
    float* S_wx       = (float*)alloc((size_t)NSUB * DCH * 4);
    float* sS_wx      = (float*)alloc((size_t)NSUB * DCH * 4);
    float* block_repr = (float*)alloc(NBLK * DCH * 4);
    float* a_s        = (float*)alloc(NBLK * DCH * 4);
    float* a_o        = (float*)alloc(NBLK * DCH * 4);
    unsigned short* W3      = (unsigned short*)alloc(128 * 768 * 2);
    unsigned short* P       = (unsigned short*)alloc((size_t)NBLK * PH * DCH * 2);
    unsigned short* convout = (unsigned short*)alloc((size_t)NBLK * 512 * DCH * 2);

    k_zero_pad<<<NBLK, 256, 0, stream>>>(P);
    k_w2t<<<384, 256, 0, stream>>>(conv_w, W3);
    k_logits2<<<NCHUNK, 256, 0, stream>>>(x, w_lw, b_lw, logits, subM);
    k_seed_max2<<<NB, 64, 0, stream>>>(subM, seedM);
    k_sums<<<NCHUNK, 256, 0, stream>>>(x, logits, seedM, exg, S_w, S_wx);
    k_seed_w<<<NB, 64, 0, stream>>>(S_w, sS_w);
    k_seed_sums2<<<NB * 8, 256, 0, stream>>>(S_wx, sS_wx);
    k_apply<<<NSUB / 2, 128, 0, stream>>>(x, exg, sS_w, sS_wx, P);
    k_conv<<<NBLK * 4, 256, 0, stream>>>(P, W3, conv_b, convout);
    k_as<<<NBLK, 256, 0, stream>>>(convout, block_repr, a_s);
    k_ao<<<NBLK, 256, 0, stream>>>(P, block_repr, a_o);
    k_fusion<<<NBLK, 128, 0, stream>>>(a_s, a_o, block_repr, fusion_w, fusion_b, out);
}

// Round 3
// 363.286 us; speedup vs baseline: 1.0649x; 1.0376x over previous
//
#include <hip/hip_runtime.h>
#include <hip/hip_bf16.h>

// Problem constants (reference: D=128, BC=64, BS=512, K=6, OV=128, B=8)
#define NB 8            // batches
#define LSEQ 32768      // BC*BS positions per batch
#define DCH 128         // channels
#define NCHUNK 1024     // 256-row chunks
#define NSUB 4096       // 64-row sub-chunks
#define NBLK 512        // B*BC conv blocks
#define PH 520          // padded rows per block (2 front + 512 + pad, rounded)
#define SCALE_F 0.08838834764831845f

typedef __bf16 bf16x8 __attribute__((ext_vector_type(8)));
typedef float f32x4 __attribute__((ext_vector_type(4)));

__device__ __forceinline__ float bf2f(unsigned short u) {
    return __uint_as_float(((unsigned)u) << 16);
}
__device__ __forceinline__ unsigned short f2bf(float f) {
    unsigned u = __float_as_uint(f);
    u += 0x7fffu + ((u >> 16) & 1u);   // round-to-nearest-even
    return (unsigned short)(u >> 16);
}

// async global->LDS DMA, 16 B per lane; LDS dest = wave-uniform base + lane*16
__device__ __forceinline__ void async_copy16(const void* gsrc, void* ldst) {
    __builtin_amdgcn_global_load_lds(
        (const __attribute__((address_space(1))) unsigned int*)gsrc,
        (__attribute__((address_space(3))) unsigned int*)ldst, 16, 0, 0);
}

// ---------------- Stage 1: logits = silu(x @ w_lw + b); per-64-row-sub max ----------------
// Column-parallel dot (LDS partials), no per-row shuffle trees.
// NOTE (R5/R6 post-mortem): reference weights are w_i = exp(l_i - cummax_i) —
// frozen at insertion, never rescaled. The cummax does NOT cancel. Keep it.
__global__ __launch_bounds__(256) void k_logits2(const float* __restrict__ x,
                                                 const float* __restrict__ w_lw,
                                                 const float* __restrict__ b_lw,
                                                 float* __restrict__ logits,
                                                 float* __restrict__ subM) {
    int chunk = blockIdx.x, t = threadIdx.x;
    int g = t & 15, rs = t >> 4;
    __shared__ float sp[256 * 17];
    __shared__ float red[256];
    float wv[8];
    #pragma unroll
    for (int e = 0; e < 8; ++e) wv[e] = w_lw[g * 8 + e];
    float bb = b_lw[0];
    size_t base = (size_t)chunk * 256 * DCH;
    for (int i = 0; i < 16; ++i) {
        int row = rs * 16 + i;
        float4 a  = *(const float4*)(x + base + (size_t)row * DCH + g * 8);
        float4 b4 = *(const float4*)(x + base + (size_t)row * DCH + g * 8 + 4);
        sp[row * 17 + g] = a.x * wv[0] + a.y * wv[1] + a.z * wv[2] + a.w * wv[3] +
                           b4.x * wv[4] + b4.y * wv[5] + b4.z * wv[6] + b4.w * wv[7];
    }
    __syncthreads();
    float s = bb;
    #pragma unroll
    for (int j = 0; j < 16; ++j) s += sp[t * 17 + j];
    float l = s / (1.f + expf(-s));          // silu
    logits[(size_t)chunk * 256 + t] = l;
    red[t] = l;
    __syncthreads();
    for (int off = 32; off >= 1; off >>= 1) {
        if ((t & 63) < off) red[t] = fmaxf(red[t], red[t + off]);
        __syncthreads();
    }
    if ((t & 63) == 0) subM[chunk * 4 + (t >> 6)] = red[t];
}

// ---------------- Stage 2: exclusive prefix-MAX over 512 subs per batch ----------------
// 3-phase wave scan: lane owns 8 subs; shfl_up inclusive scan; rewalk.
__global__ __launch_bounds__(64) void k_seed_max2(const float* __restrict__ subM,
                                                  float* __restrict__ seedM) {
    int b = blockIdx.x, lane = threadIdx.x;
    const float* src = subM + b * 512;
    float* dst = seedM + b * 512;
    float v[8];
    float m = -INFINITY;
    #pragma unroll
    for (int j = 0; j < 8; ++j) { v[j] = src[lane * 8 + j]; m = fmaxf(m, v[j]); }
    float incl = m;
    #pragma unroll
    for (int off = 1; off < 64; off <<= 1) {
        float o = __shfl_up(incl, off, 64);
        if (lane >= off) incl = fmaxf(incl, o);
    }
    float ex = __shfl_up(incl, 1, 64);
    if (lane == 0) ex = -INFINITY;
    float run = ex;
    #pragma unroll
    for (int j = 0; j < 8; ++j) { dst[lane * 8 + j] = run; run = fmaxf(run, v[j]); }
}

// ---------------- Stage 3: w_i = exp(l_i - max(seedM, cummax_loc)); sub sums ----------------
__global__ __launch_bounds__(256) void k_sums(const float* __restrict__ x,
                                              const float* __restrict__ logits,
                                              const float* __restrict__ seedM,
                                              float* __restrict__ exg,
                                              float* __restrict__ S_w,
                                              float* __restrict__ S_wx) {
    int chunk = blockIdx.x, t = threadIdx.x;
    int g = t & 15, rs = t >> 4;
    __shared__ float llog[256];
    __shared__ float wbuf[256];
    __shared__ float red[256];
    __shared__ float rp[16 * 130];
    llog[t] = logits[(size_t)chunk * 256 + t];
    __syncthreads();
    if (t < 4) {                                // serial 64-deep running max per sub
        float M = seedM[chunk * 4 + t];
        float m = -INFINITY;
        for (int i = 0; i < 64; ++i) {
            float l = llog[t * 64 + i];
            m = fmaxf(m, l);
            wbuf[t * 64 + i] = expf(l - fmaxf(M, m));
        }
    }
    __syncthreads();
    float w_t = wbuf[t];
    exg[(size_t)chunk * 256 + t] = w_t;
    red[t] = w_t;
    __syncthreads();
    for (int off = 32; off >= 1; off >>= 1) {
        if ((t & 63) < off) red[t] += red[t + off];
        __syncthreads();
    }
    if ((t & 63) == 0) S_w[chunk * 4 + (t >> 6)] = red[t];
    // column-parallel S_wx: thread (g,rs) covers rows rs*16..+15 (all in sub rs>>2)
    float acc[8];
    #pragma unroll
    for (int e = 0; e < 8; ++e) acc[e] = 0.f;
    size_t base = (size_t)chunk * 256 * DCH;
    for (int i = 0; i < 16; ++i) {
        int row = rs * 16 + i;
        float w = wbuf[row];
        float4 a  = *(const float4*)(x + base + (size_t)row * DCH + g * 8);
        float4 b4 = *(const float4*)(x + base + (size_t)row * DCH + g * 8 + 4);
        acc[0] += w * a.x;  acc[1] += w * a.y;  acc[2] += w * a.z;  acc[3] += w * a.w;
        acc[4] += w * b4.x; acc[5] += w * b4.y; acc[6] += w * b4.z; acc[7] += w * b4.w;
    }
    #pragma unroll
    for (int e = 0; e < 8; ++e) rp[rs * 130 + g * 8 + e] = acc[e];
    __syncthreads();
    #pragma unroll
    for (int k = 0; k < 2; ++k) {
        int idx = k * 256 + t;                 // 4 subs x 128 ch
        int sub = idx >> 7, c = idx & 127;
        float sm = rp[(sub * 4 + 0) * 130 + c] + rp[(sub * 4 + 1) * 130 + c] +
                   rp[(sub * 4 + 2) * 130 + c] + rp[(sub * 4 + 3) * 130 + c];
        S_wx[((size_t)chunk * 4 + sub) * DCH + c] = sm;
    }
}

// ---------------- Stage 4a: exclusive prefix-SUM of S_w (512/batch), wave scan ----------------
__global__ __launch_bounds__(64) void k_seed_w(const float* __restrict__ S_w,
                                               float* __restrict__ sS_w) {
    int b = blockIdx.x, lane = threadIdx.x;
    const float* src = S_w + b * 512;
    float* dst = sS_w + b * 512;
    float v[8];
    float tot = 0.f;
    #pragma unroll
    for (int j = 0; j < 8; ++j) { v[j] = src[lane * 8 + j]; tot += v[j]; }
    float incl = tot;
    #pragma unroll
    for (int off = 1; off < 64; off <<= 1) {
        float o = __shfl_up(incl, off, 64);
        if (lane >= off) incl += o;
    }
    float ex = __shfl_up(incl, 1, 64);
    if (lane == 0) ex = 0.f;
    float run = ex;
    #pragma unroll
    for (int j = 0; j < 8; ++j) { dst[lane * 8 + j] = run; run += v[j]; }
}

// ---------------- Stage 4b: exclusive prefix-SUM of S_wx per channel, 3-phase ----------------
// block = (batch, 16-channel group); thread = (segment of 32 subs, channel)
__global__ __launch_bounds__(256) void k_seed_sums2(const float* __restrict__ S_wx,
                                                    float* __restrict__ sS_wx) {
    int b = blockIdx.x >> 3, cg = blockIdx.x & 7;
    int t = threadIdx.x;
    int cl = t & 15, seg = t >> 4;
    int c = cg * 16 + cl;
    __shared__ float tots[16][17];
    const float* src = S_wx + (size_t)b * 512 * DCH + c;
    float* dst = sS_wx + (size_t)b * 512 * DCH + c;
    int s0 = seg * 32;
    float tot = 0.f;
    for (int j = 0; j < 32; ++j) tot += src[(size_t)(s0 + j) * DCH];
    tots[seg][cl] = tot;
    __syncthreads();
    if (t < 16) {
        float run = 0.f;
        for (int s = 0; s < 16; ++s) { float tmp = tots[s][t]; tots[s][t] = run; run += tmp; }
    }
    __syncthreads();
    float run = tots[seg][cl];
    for (int j = 0; j < 32; ++j) {
        float val = src[(size_t)(s0 + j) * DCH];
        dst[(size_t)(s0 + j) * DCH] = run;
        run += val;
    }
}

// ---------------- merged init: zero halo rows of P + weight repack W3 ----------------
// W3 flat index f = (((kt*2+ks)*4 + kchunk)*128 + o)*8 + e
//   maps to conv_w[o][ i ][ kn ],  i = (kt&1)*64 + (ks*4+kchunk)*8 + e,  kn = kt>>1.
// A wave's B-fragment load (fixed kt,ks,ni) is then 4 x 256 B coalesced segments.
__global__ __launch_bounds__(256) void k_init(const float* __restrict__ conv_w,
                                              unsigned short* __restrict__ W3,
                                              unsigned short* __restrict__ P) {
    int n = blockIdx.x, t = threadIdx.x;
    for (int i = t; i < 1024; i += 256) {
        int rr = i >> 7;                       // 0..7
        int row = (rr < 2) ? rr : 512 + rr;    // rows 0,1,514..519
        P[(n * PH + row) * DCH + (i & 127)] = 0;
    }
    int idx = n * 256 + t;                     // blocks 0..383 cover 98304 elems
    if (idx < 98304) {
        int e  = idx & 7;
        int o  = (idx >> 3) & 127;
        int kc = (idx >> 10) & 3;
        int kt2 = idx >> 12;                   // 0..23 = kt*2+ks
        int kt = kt2 >> 1, ks = kt2 & 1;
        int i  = (kt & 1) * 64 + (ks * 4 + kc) * 8 + e;
        int kn = kt >> 1;
        W3[idx] = f2bf(conv_w[(o * 128 + i) * 6 + kn]);
    }
}

// ---------------- Stage 5: apply scan -> prefix_x, write bf16 padded P ----------------
// One wave per 64-row sub-chunk; lane owns a channel pair; fp32 x input.
__global__ __launch_bounds__(128) void k_apply(const float* __restrict__ x,
                                               const float* __restrict__ exg,
                                               const float* __restrict__ sS_w,
                                               const float* __restrict__ sS_wx,
                                               unsigned short* __restrict__ P) {
    int t = threadIdx.x, w = t >> 6, lane = t & 63;
    int s = blockIdx.x * 2 + w;                // sub-chunk id
    int b = s >> 9, sb = s & 511;
    __shared__ float e2[128];
    e2[t] = exg[(size_t)blockIdx.x * 128 + t]; // both waves' w values
    float2 axx = *(const float2*)(sS_wx + (size_t)s * DCH + 2 * lane);
    float aex = sS_w[s];
    __syncthreads();
    const float* es = e2 + w * 64;
    int pib0 = sb * 64;
    int n = b * 64 + (pib0 >> 9);
    int row0 = (pib0 & 511) + 2;
    const float* xp = x + ((size_t)b * LSEQ + pib0) * DCH + 2 * lane;
    unsigned short* pp = P + ((size_t)n * PH + row0) * DCH + 2 * lane;
    for (int j = 0; j < 64; ++j) {
        float e = es[j];
        aex += e;
        float2 xv = *(const float2*)xp;
        axx.x += e * xv.x;
        axx.y += e * xv.y;
        float inv = 1.f / aex;
        unsigned pk = ((unsigned)f2bf(axx.y * inv + xv.y) << 16) | f2bf(axx.x * inv + xv.x);
        *(unsigned*)pp = pk;
        xp += DCH;
        pp += DCH;
    }
}

// ---------------- Stage 6: conv as bf16 MFMA GEMM (128x128 tile, K=768) ----------------
// A-tile double-buffered in LDS (2 x 16 KB) with ONE barrier per K-step (T3 minimum
// 2-phase: DMA for kt+1 issued before compute of kt; the single __syncthreads()
// drains vmcnt AND protects buffer reuse). B operands bypass LDS: W3 (192 KB, shared
// by all 2048 workgroups) is L2-resident; fragments load straight into registers
// (double-buffered, static indices via full unroll).
__global__ __launch_bounds__(256) void k_conv(const unsigned short* __restrict__ P,
                                              const unsigned short* __restrict__ W3,
                                              const float* __restrict__ conv_b,
                                              unsigned short* __restrict__ convout) {
    int n = blockIdx.x >> 2;
    int h0 = (blockIdx.x & 3) * 128;
    __shared__ __align__(16) unsigned short lds[128 * 136];  // 34816 B; loop uses first 32 KB as A dbuf
    char* abuf0 = (char*)lds;
    char* abuf1 = (char*)lds + 16384;
    int t = threadIdx.x;
    int wave = t >> 6, lane = t & 63;
    f32x4 acc[4][4] = {};
    const unsigned short* Pn = P + (size_t)n * PH * DCH;
    int wm = (wave >> 1) * 64, wn = (wave & 1) * 64;
    int cpos = lane & 7;                      // LDS chunk position this lane fills (DMA)
    int kchunk = lane >> 4;                   // 0..3 (MFMA k-slice group)
    int bcol = wn + (lane & 15);              // B out-channel base (+ni*16)

    bf16x8 breg[2][8];

    auto stageA = [&](int kt, char* dst) {
        int kn = kt >> 1, c0 = (kt & 1) * 64;
        #pragma unroll
        for (int j = 0; j < 4; ++j) {
            int r = (wave * 4 + j) * 8 + (lane >> 3);   // LDS row 0..127
            int gr = h0 + kn + r;                       // global padded row
            int csrcA = cpos ^ (gr & 7);                // source-side swizzle
            async_copy16(Pn + (size_t)gr * DCH + c0 + csrcA * 8,
                         dst + (wave * 4 + j) * 1024 + lane * 16);
        }
    };
    auto loadB = [&](int kt, bf16x8* dstB) {
        #pragma unroll
        for (int ks = 0; ks < 2; ++ks)
            #pragma unroll
            for (int ni = 0; ni < 4; ++ni)
                dstB[ks * 4 + ni] = *(const bf16x8*)(
                    W3 + (size_t)((kt * 2 + ks) * 4 + kchunk) * 1024 + (bcol + ni * 16) * 8);
    };

    // prologue: stage kt=0 (A via DMA, B via L2->reg)
    stageA(0, abuf0);
    loadB(0, breg[0]);
    __syncthreads();                           // drains vmcnt(0): buf0 + breg[0] ready

    #pragma unroll
    for (int kt = 0; kt < 12; ++kt) {
        char* cbuf = (kt & 1) ? abuf1 : abuf0;
        if (kt < 11) {
            stageA(kt + 1, (kt & 1) ? abuf0 : abuf1);  // DMA next tile into other buffer
            loadB(kt + 1, breg[(kt + 1) & 1]);         // prefetch next B frags from L2
        }
        int kn = kt >> 1;
        #pragma unroll
        for (int ks = 0; ks < 2; ++ks) {
            bf16x8 af[4];
            #pragma unroll
            for (int mi = 0; mi < 4; ++mi) {
                int rA = wm + mi * 16 + (lane & 15);
                int pA = (ks * 4 + kchunk) ^ ((kn + rA) & 7);
                af[mi] = *(const bf16x8*)(cbuf + rA * 128 + pA * 16);
            }
            #pragma unroll
            for (int mi = 0; mi < 4; ++mi)
                #pragma unroll
                for (int ni = 0; ni < 4; ++ni)
                    acc[mi][ni] = __builtin_amdgcn_mfma_f32_16x16x32_bf16(af[mi],
                                                                          breg[kt & 1][ks * 4 + ni],
                                                                          acc[mi][ni], 0, 0, 0);
        }
        __syncthreads();   // publishes buf[kt+1] (vmcnt) + all reads of buf[kt] done
    }
    // C/D layout: col=lane&15, row=(lane>>4)*4+reg  [m89-verified]
    #pragma unroll
    for (int mi = 0; mi < 4; ++mi)
        #pragma unroll
        for (int ni = 0; ni < 4; ++ni) {
            int col = wn + ni * 16 + (lane & 15);
            float bias = conv_b[col];
            #pragma unroll
            for (int r = 0; r < 4; ++r) {
                int row = wm + mi * 16 + (lane >> 4) * 4 + r;
                lds[row * 136 + col] = f2bf(acc[mi][ni][r] + bias);
            }
        }
    __syncthreads();
    // coalesced store: 2048 granules of 16 B
    size_t base = (size_t)(n * 512 + h0) * DCH;
    #pragma unroll
    for (int it = 0; it < 8; ++it) {
        int idx = it * 256 + t;
        int row = idx >> 4, g = idx & 15;
        uint4 v = *(const uint4*)(lds + row * 136 + g * 8);
        *(uint4*)(convout + base + (size_t)row * DCH + g * 8) = v;
    }
}

// ---------------- Stage 7-9 fused tail: block_repr + a_s + a_o + fusion, one block per n ----
// All three old kernels (k_as, k_ao, k_fusion) had the same per-n chain; fusing keeps
// br/a_s/a_o in LDS (no HBM round-trip, no extra launches). LDS budget 39.4 KB
// -> 4 blocks/CU, same as old k_as. fu aliases sp tail (barrier-separated lifetime).
__global__ __launch_bounds__(256) void k_tail(const unsigned short* __restrict__ conv,
                                              const unsigned short* __restrict__ P,
                                              const float* __restrict__ fusion_w,
                                              const float* __restrict__ fusion_b,
                                              float* __restrict__ block_repr,
                                              float* __restrict__ out) {
    int n = blockIdx.x, t = threadIdx.x;
    int g = t & 15, rs = t >> 4;
    int b = n >> 6, c = n & 63;
    __shared__ __align__(16) float sp[512 * 17];   // partials / rp[16][130] / red / fu / comb
    __shared__ float s[512];
    __shared__ float br[128];
    __shared__ float as_l[128];
    __shared__ float ao_l[128];
    __shared__ float red[128];
    __shared__ int rb[128];
    float* rp = sp;                                 // [16][130] view
    const unsigned short* base = conv + (size_t)n * 512 * DCH;

    // ================= phase A: block_repr + a_s (from convout) =================
    // ---- A0: column max ----
    float m[8];
    #pragma unroll
    for (int e = 0; e < 8; ++e) m[e] = -INFINITY;
    for (int i = 0; i < 32; ++i) {
        int row = i * 16 + rs;
        uint4 v = *(const uint4*)(base + row * DCH + g * 8);
        unsigned vv[4] = {v.x, v.y, v.z, v.w};
        #pragma unroll
        for (int e = 0; e < 4; ++e) {
            m[2 * e]     = fmaxf(m[2 * e],     bf2f((unsigned short)(vv[e] & 0xffff)));
            m[2 * e + 1] = fmaxf(m[2 * e + 1], bf2f((unsigned short)(vv[e] >> 16)));
        }
    }
    #pragma unroll
    for (int e = 0; e < 8; ++e) rp[rs * 130 + g * 8 + e] = m[e];
    __syncthreads();
    if (t < 128) {
        float bm = rp[t];
        #pragma unroll
        for (int r2 = 1; r2 < 16; ++r2) bm = fmaxf(bm, rp[r2 * 130 + t]);
        br[t] = bm;
        block_repr[n * DCH + t] = bm;   // kept for debugging parity; cheap (256 KB)
    }
    __syncthreads();

    // ---- A1: scores s[row] = (conv[row] . br) * SCALE ----
    float brv[8];
    #pragma unroll
    for (int e = 0; e < 8; ++e) brv[e] = br[g * 8 + e];
    for (int i = 0; i < 32; ++i) {
        int row = i * 16 + rs;
        uint4 v = *(const uint4*)(base + row * DCH + g * 8);
        unsigned vv[4] = {v.x, v.y, v.z, v.w};
        float p = 0.f;
        #pragma unroll
        for (int e = 0; e < 4; ++e) {
            p += bf2f((unsigned short)(vv[e] & 0xffff)) * brv[2 * e];
            p += bf2f((unsigned short)(vv[e] >> 16))    * brv[2 * e + 1];
        }
        sp[row * 17 + g] = p;
    }
    __syncthreads();
    #pragma unroll
    for (int rr = 0; rr < 2; ++rr) {
        int row = t * 2 + rr;
        float p = 0.f;
        #pragma unroll
        for (int j = 0; j < 16; ++j) p += sp[row * 17 + j];
        s[row] = p * SCALE_F;
    }
    __syncthreads();

    // ---- A2: softmax over s[512] (scratch reuses sp after scores consumed) ----
    float* redA = sp;
    float mm = fmaxf(s[t], s[t + 256]);
    __syncthreads();          // all score reads of sp done before overwrite
    redA[t] = mm;
    __syncthreads();
    for (int off = 128; off > 0; off >>= 1) {
        if (t < off) redA[t] = fmaxf(redA[t], redA[t + off]);
        __syncthreads();
    }
    float smax = redA[0];
    __syncthreads();
    float e0 = expf(s[t] - smax), e1 = expf(s[t + 256] - smax);
    redA[t] = e0 + e1;
    __syncthreads();
    for (int off = 128; off > 0; off >>= 1) {
        if (t < off) redA[t] += redA[t + off];
        __syncthreads();
    }
    float inv = 1.f / redA[0];
    __syncthreads();
    s[t] = e0 * inv;
    s[t + 256] = e1 * inv;
    __syncthreads();

    // ---- A3: weighted sum -> a_s (stays in LDS) ----
    float acc[8];
    #pragma unroll
    for (int e = 0; e < 8; ++e) acc[e] = 0.f;
    for (int i = 0; i < 32; ++i) {
        int row = i * 16 + rs;
        float w = s[row];
        uint4 v = *(const uint4*)(base + row * DCH + g * 8);
        unsigned vv[4] = {v.x, v.y, v.z, v.w};
        #pragma unroll
        for (int e = 0; e < 4; ++e) {
            acc[2 * e]     += w * bf2f((unsigned short)(vv[e] & 0xffff));
            acc[2 * e + 1] += w * bf2f((unsigned short)(vv[e] >> 16));
        }
    }
    #pragma unroll
    for (int e = 0; e < 8; ++e) rp[rs * 130 + g * 8 + e] = acc[e];
    __syncthreads();
    if (t < 128) {
        float p = 0.f;
        #pragma unroll
        for (int r2 = 0; r2 < 16; ++r2) p += rp[r2 * 130 + t];
        as_l[t] = p;
    }

    // ================= phase B: a_o = attn(br, xbo, xbo) (from P) =================
    if (t < 128) {
        int pib = (c + 1) * 512 - 64 + t;       // window straddling block end
        pib = min(pib, LSEQ - 1);               // edge-clamp at sequence end
        int n2 = b * 64 + (pib >> 9);
        int row = (pib & 511) + 2;
        rb[t] = (n2 * PH + row) * DCH;
    }
    __syncthreads();                            // as_l published; rb ready; sp free
    #pragma unroll
    for (int r = 0; r < 8; ++r) {
        int row = rs * 8 + r;
        uint4 v = *(const uint4*)(P + rb[row] + g * 8);
        unsigned vv[4] = {v.x, v.y, v.z, v.w};
        float p = 0.f;
        #pragma unroll
        for (int e = 0; e < 4; ++e) {
            p += bf2f((unsigned short)(vv[e] & 0xffff)) * brv[2 * e];
            p += bf2f((unsigned short)(vv[e] >> 16))    * brv[2 * e + 1];
        }
        sp[row * 17 + g] = p;
    }
    __syncthreads();
    if (t < 128) {
        float p = 0.f;
        #pragma unroll
        for (int j = 0; j < 16; ++j) p += sp[t * 17 + j];
        s[t] = p * SCALE_F;
        red[t] = s[t];
    }
    __syncthreads();
    for (int off = 64; off > 0; off >>= 1) {
        if (t < off) red[t] = fmaxf(red[t], red[t + off]);
        __syncthreads();
    }
    float smaxB = red[0];
    __syncthreads();
    if (t < 128) {
        float e = expf(s[t] - smaxB);
        s[t] = e;
        red[t] = e;
    }
    __syncthreads();
    for (int off = 64; off > 0; off >>= 1) {
        if (t < off) red[t] += red[t + off];
        __syncthreads();
    }
    float invB = 1.f / red[0];
    __syncthreads();
    if (t < 128) s[t] *= invB;
    __syncthreads();
    float accB[8];
    #pragma unroll
    for (int e = 0; e < 8; ++e) accB[e] = 0.f;
    #pragma unroll
    for (int r = 0; r < 8; ++r) {
        int row = rs * 8 + r;
        float w = s[row];
        uint4 v = *(const uint4*)(P + rb[row] + g * 8);
        unsigned vv[4] = {v.x, v.y, v.z, v.w};
        #pragma unroll
        for (int e = 0; e < 4; ++e) {
            accB[2 * e]     += w * bf2f((unsigned short)(vv[e] & 0xffff));
            accB[2 * e + 1] += w * bf2f((unsigned short)(vv[e] >> 16));
        }
    }
    #pragma unroll
    for (int e = 0; e < 8; ++e) sp[rs * 130 + g * 8 + e] = accB[e];
    __syncthreads();
    if (t < 128) {
        float p = 0.f;
        #pragma unroll
        for (int r2 = 0; r2 < 16; ++r2) p += sp[r2 * 130 + t];
        ao_l[t] = p;
    }
    __syncthreads();

    // ================= phase C: out = concat(a_s,a_o,br) @ fusion_w + b =================
    float* fu = sp + 8320;                      // 384 floats, disjoint from comb region
    if (t < 128) {
        fu[t] = as_l[t];
        fu[128 + t] = ao_l[t];
        fu[256 + t] = br[t];
    }
    __syncthreads();
    {
        int col = t & 127, h = t >> 7;          // 2 threads per output column
        float a2 = (h == 0) ? fusion_b[col] : 0.f;
        for (int j = h * 192; j < h * 192 + 192; ++j)
            a2 += fu[j] * fusion_w[j * DCH + col];
        sp[h * 128 + col] = a2;
    }
    __syncthreads();
    if (t < 128) {
        float v = sp[t] + sp[128 + t];
        out[n * DCH + t] = v;
        out[NB * 64 * DCH + n * DCH + t] = v;   // second tuple element (out, out)
    }
}

extern "C" void kernel_launch(void* const* d_in, const int* in_sizes, int n_in,
                              void* d_out, int out_size, void* d_ws, size_t ws_size,
                              hipStream_t stream) {
    const float* x        = (const float*)d_in[0];
    const float* w_lw     = (const float*)d_in[1];
    const float* b_lw     = (const float*)d_in[2];
    const float* conv_w   = (const float*)d_in[3];
    const float* conv_b   = (const float*)d_in[4];
    const float* fusion_w = (const float*)d_in[5];
    const float* fusion_b = (const float*)d_in[6];
    float* out = (float*)d_out;

    char* ws = (char*)d_ws;
    size_t off = 0;
    auto alloc = [&](size_t bytes) { char* p = ws + off; off += (bytes + 255) & ~(size_t)255; return p; };
    float* logits     = (float*)alloc(NB * LSEQ * 4);
    float* exg        = (float*)alloc(NB * LSEQ * 4);
    float* subM       = (float*)alloc(NSUB * 4);
    float* seedM      = (float*)alloc(NSUB * 4);
    float* S_w        = (float*)alloc(NSUB * 4);
    float* sS_w       = (float*)alloc(NSUB * 4);
    float* S_wx       = (float*)alloc((size_t)NSUB * DCH * 4);
    float* sS_wx      = (float*)alloc((size_t)NSUB * DCH * 4);
    float* block_repr = (float*)alloc(NBLK * DCH * 4);
    unsigned short* W3      = (unsigned short*)alloc(128 * 768 * 2);
    unsigned short* P       = (unsigned short*)alloc((size_t)NBLK * PH * DCH * 2);
    unsigned short* convout = (unsigned short*)alloc((size_t)NBLK * 512 * DCH * 2);

    k_init<<<NBLK, 256, 0, stream>>>(conv_w, W3, P);
    k_logits2<<<NCHUNK, 256, 0, stream>>>(x, w_lw, b_lw, logits, subM);
    k_seed_max2<<<NB, 64, 0, stream>>>(subM, seedM);
    k_sums<<<NCHUNK, 256, 0, stream>>>(x, logits, seedM, exg, S_w, S_wx);
    k_seed_w<<<NB, 64, 0, stream>>>(S_w, sS_w);
    k_seed_sums2<<<NB * 8, 256, 0, stream>>>(S_wx, sS_wx);
    k_apply<<<NSUB / 2, 128, 0, stream>>>(x, exg, sS_w, sS_wx, P);
    k_conv<<<NBLK * 4, 256, 0, stream>>>(P, W3, conv_b, convout);
    k_tail<<<NBLK, 256, 0, stream>>>(convout, P, fusion_w, fusion_b, block_repr, out);
}

// Round 4
// 353.350 us; speedup vs baseline: 1.0949x; 1.0281x over previous
//
#include <hip/hip_runtime.h>
#include <hip/hip_bf16.h>

// Problem constants (reference: D=128, BC=64, BS=512, K=6, OV=128, B=8)
#define NB 8            // batches
#define LSEQ 32768      // BC*BS positions per batch
#define DCH 128         // channels
#define NCHUNK 1024     // 256-row chunks
#define NSUB 4096       // 64-row sub-chunks
#define NBLK 512        // B*BC conv blocks
#define PH 520          // padded rows per block (2 front + 512 + pad, rounded)
#define SCALE_F 0.08838834764831845f

typedef __bf16 bf16x8 __attribute__((ext_vector_type(8)));
typedef float f32x4 __attribute__((ext_vector_type(4)));

__device__ __forceinline__ float bf2f(unsigned short u) {
    return __uint_as_float(((unsigned)u) << 16);
}
__device__ __forceinline__ unsigned short f2bf(float f) {
    unsigned u = __float_as_uint(f);
    u += 0x7fffu + ((u >> 16) & 1u);   // round-to-nearest-even
    return (unsigned short)(u >> 16);
}

// async global->LDS DMA, 16 B per lane; LDS dest = wave-uniform base + lane*16
__device__ __forceinline__ void async_copy16(const void* gsrc, void* ldst) {
    __builtin_amdgcn_global_load_lds(
        (const __attribute__((address_space(1))) unsigned int*)gsrc,
        (__attribute__((address_space(3))) unsigned int*)ldst, 16, 0, 0);
}

// ---------------- Stage 1: logits = silu(x @ w_lw + b); per-64-row-sub max ----------------
// Column-parallel dot (LDS partials), no per-row shuffle trees.
// NOTE (R5/R6 post-mortem): reference weights are w_i = exp(l_i - cummax_i) —
// frozen at insertion, never rescaled. The cummax does NOT cancel. Keep it.
__global__ __launch_bounds__(256) void k_logits2(const float* __restrict__ x,
                                                 const float* __restrict__ w_lw,
                                                 const float* __restrict__ b_lw,
                                                 float* __restrict__ logits,
                                                 float* __restrict__ subM) {
    int chunk = blockIdx.x, t = threadIdx.x;
    int g = t & 15, rs = t >> 4;
    __shared__ float sp[256 * 17];
    __shared__ float red[256];
    float wv[8];
    #pragma unroll
    for (int e = 0; e < 8; ++e) wv[e] = w_lw[g * 8 + e];
    float bb = b_lw[0];
    size_t base = (size_t)chunk * 256 * DCH;
    for (int i = 0; i < 16; ++i) {
        int row = rs * 16 + i;
        float4 a  = *(const float4*)(x + base + (size_t)row * DCH + g * 8);
        float4 b4 = *(const float4*)(x + base + (size_t)row * DCH + g * 8 + 4);
        sp[row * 17 + g] = a.x * wv[0] + a.y * wv[1] + a.z * wv[2] + a.w * wv[3] +
                           b4.x * wv[4] + b4.y * wv[5] + b4.z * wv[6] + b4.w * wv[7];
    }
    __syncthreads();
    float s = bb;
    #pragma unroll
    for (int j = 0; j < 16; ++j) s += sp[t * 17 + j];
    float l = s / (1.f + expf(-s));          // silu
    logits[(size_t)chunk * 256 + t] = l;
    red[t] = l;
    __syncthreads();
    for (int off = 32; off >= 1; off >>= 1) {
        if ((t & 63) < off) red[t] = fmaxf(red[t], red[t + off]);
        __syncthreads();
    }
    if ((t & 63) == 0) subM[chunk * 4 + (t >> 6)] = red[t];
}

// ---------------- Stage 2: exclusive prefix-MAX over 512 subs per batch ----------------
// 3-phase wave scan: lane owns 8 subs; shfl_up inclusive scan; rewalk.
__global__ __launch_bounds__(64) void k_seed_max2(const float* __restrict__ subM,
                                                  float* __restrict__ seedM) {
    int b = blockIdx.x, lane = threadIdx.x;
    const float* src = subM + b * 512;
    float* dst = seedM + b * 512;
    float v[8];
    float m = -INFINITY;
    #pragma unroll
    for (int j = 0; j < 8; ++j) { v[j] = src[lane * 8 + j]; m = fmaxf(m, v[j]); }
    float incl = m;
    #pragma unroll
    for (int off = 1; off < 64; off <<= 1) {
        float o = __shfl_up(incl, off, 64);
        if (lane >= off) incl = fmaxf(incl, o);
    }
    float ex = __shfl_up(incl, 1, 64);
    if (lane == 0) ex = -INFINITY;
    float run = ex;
    #pragma unroll
    for (int j = 0; j < 8; ++j) { dst[lane * 8 + j] = run; run = fmaxf(run, v[j]); }
}

// ---------------- Stage 3: w_i = exp(l_i - max(seedM, cummax_loc)); sub sums ----------------
__global__ __launch_bounds__(256) void k_sums(const float* __restrict__ x,
                                              const float* __restrict__ logits,
                                              const float* __restrict__ seedM,
                                              float* __restrict__ exg,
                                              float* __restrict__ S_w,
                                              float* __restrict__ S_wx) {
    int chunk = blockIdx.x, t = threadIdx.x;
    int g = t & 15, rs = t >> 4;
    __shared__ float llog[256];
    __shared__ float wbuf[256];
    __shared__ float red[256];
    __shared__ float rp[16 * 130];
    llog[t] = logits[(size_t)chunk * 256 + t];
    __syncthreads();
    if (t < 4) {                                // serial 64-deep running max per sub
        float M = seedM[chunk * 4 + t];
        float m = -INFINITY;
        for (int i = 0; i < 64; ++i) {
            float l = llog[t * 64 + i];
            m = fmaxf(m, l);
            wbuf[t * 64 + i] = expf(l - fmaxf(M, m));
        }
    }
    __syncthreads();
    float w_t = wbuf[t];
    exg[(size_t)chunk * 256 + t] = w_t;
    red[t] = w_t;
    __syncthreads();
    for (int off = 32; off >= 1; off >>= 1) {
        if ((t & 63) < off) red[t] += red[t + off];
        __syncthreads();
    }
    if ((t & 63) == 0) S_w[chunk * 4 + (t >> 6)] = red[t];
    // column-parallel S_wx: thread (g,rs) covers rows rs*16..+15 (all in sub rs>>2)
    float acc[8];
    #pragma unroll
    for (int e = 0; e < 8; ++e) acc[e] = 0.f;
    size_t base = (size_t)chunk * 256 * DCH;
    for (int i = 0; i < 16; ++i) {
        int row = rs * 16 + i;
        float w = wbuf[row];
        float4 a  = *(const float4*)(x + base + (size_t)row * DCH + g * 8);
        float4 b4 = *(const float4*)(x + base + (size_t)row * DCH + g * 8 + 4);
        acc[0] += w * a.x;  acc[1] += w * a.y;  acc[2] += w * a.z;  acc[3] += w * a.w;
        acc[4] += w * b4.x; acc[5] += w * b4.y; acc[6] += w * b4.z; acc[7] += w * b4.w;
    }
    #pragma unroll
    for (int e = 0; e < 8; ++e) rp[rs * 130 + g * 8 + e] = acc[e];
    __syncthreads();
    #pragma unroll
    for (int k = 0; k < 2; ++k) {
        int idx = k * 256 + t;                 // 4 subs x 128 ch
        int sub = idx >> 7, c = idx & 127;
        float sm = rp[(sub * 4 + 0) * 130 + c] + rp[(sub * 4 + 1) * 130 + c] +
                   rp[(sub * 4 + 2) * 130 + c] + rp[(sub * 4 + 3) * 130 + c];
        S_wx[((size_t)chunk * 4 + sub) * DCH + c] = sm;
    }
}

// ---------------- Stage 4a: exclusive prefix-SUM of S_w (512/batch), wave scan ----------------
__global__ __launch_bounds__(64) void k_seed_w(const float* __restrict__ S_w,
                                               float* __restrict__ sS_w) {
    int b = blockIdx.x, lane = threadIdx.x;
    const float* src = S_w + b * 512;
    float* dst = sS_w + b * 512;
    float v[8];
    float tot = 0.f;
    #pragma unroll
    for (int j = 0; j < 8; ++j) { v[j] = src[lane * 8 + j]; tot += v[j]; }
    float incl = tot;
    #pragma unroll
    for (int off = 1; off < 64; off <<= 1) {
        float o = __shfl_up(incl, off, 64);
        if (lane >= off) incl += o;
    }
    float ex = __shfl_up(incl, 1, 64);
    if (lane == 0) ex = 0.f;
    float run = ex;
    #pragma unroll
    for (int j = 0; j < 8; ++j) { dst[lane * 8 + j] = run; run += v[j]; }
}

// ---------------- Stage 4b: exclusive prefix-SUM of S_wx per channel, 3-phase ----------------
// block = (batch, 16-channel group); thread = (segment of 32 subs, channel)
__global__ __launch_bounds__(256) void k_seed_sums2(const float* __restrict__ S_wx,
                                                    float* __restrict__ sS_wx) {
    int b = blockIdx.x >> 3, cg = blockIdx.x & 7;
    int t = threadIdx.x;
    int cl = t & 15, seg = t >> 4;
    int c = cg * 16 + cl;
    __shared__ float tots[16][17];
    const float* src = S_wx + (size_t)b * 512 * DCH + c;
    float* dst = sS_wx + (size_t)b * 512 * DCH + c;
    int s0 = seg * 32;
    float tot = 0.f;
    for (int j = 0; j < 32; ++j) tot += src[(size_t)(s0 + j) * DCH];
    tots[seg][cl] = tot;
    __syncthreads();
    if (t < 16) {
        float run = 0.f;
        for (int s = 0; s < 16; ++s) { float tmp = tots[s][t]; tots[s][t] = run; run += tmp; }
    }
    __syncthreads();
    float run = tots[seg][cl];
    for (int j = 0; j < 32; ++j) {
        float val = src[(size_t)(s0 + j) * DCH];
        dst[(size_t)(s0 + j) * DCH] = run;
        run += val;
    }
}

// ---------------- merged init: zero halo rows of P + weight repack W3 ----------------
// W3 flat index f = (((kt*2+ks)*4 + kchunk)*128 + o)*8 + e
//   maps to conv_w[o][ i ][ kn ],  i = (kt&1)*64 + (ks*4+kchunk)*8 + e,  kn = kt>>1.
// A wave's B-fragment load (fixed kt,ks,ni) is then 4 x 256 B coalesced segments.
__global__ __launch_bounds__(256) void k_init(const float* __restrict__ conv_w,
                                              unsigned short* __restrict__ W3,
                                              unsigned short* __restrict__ P) {
    int n = blockIdx.x, t = threadIdx.x;
    for (int i = t; i < 1024; i += 256) {
        int rr = i >> 7;                       // 0..7
        int row = (rr < 2) ? rr : 512 + rr;    // rows 0,1,514..519
        P[(n * PH + row) * DCH + (i & 127)] = 0;
    }
    int idx = n * 256 + t;                     // blocks 0..383 cover 98304 elems
    if (idx < 98304) {
        int e  = idx & 7;
        int o  = (idx >> 3) & 127;
        int kc = (idx >> 10) & 3;
        int kt2 = idx >> 12;                   // 0..23 = kt*2+ks
        int kt = kt2 >> 1, ks = kt2 & 1;
        int i  = (kt & 1) * 64 + (ks * 4 + kc) * 8 + e;
        int kn = kt >> 1;
        W3[idx] = f2bf(conv_w[(o * 128 + i) * 6 + kn]);
    }
}

// ---------------- Stage 5: apply scan -> prefix_x, write bf16 padded P ----------------
// One wave per 64-row sub-chunk; lane owns a channel pair; fp32 x input.
__global__ __launch_bounds__(128) void k_apply(const float* __restrict__ x,
                                               const float* __restrict__ exg,
                                               const float* __restrict__ sS_w,
                                               const float* __restrict__ sS_wx,
                                               unsigned short* __restrict__ P) {
    int t = threadIdx.x, w = t >> 6, lane = t & 63;
    int s = blockIdx.x * 2 + w;                // sub-chunk id
    int b = s >> 9, sb = s & 511;
    __shared__ float e2[128];
    e2[t] = exg[(size_t)blockIdx.x * 128 + t]; // both waves' w values
    float2 axx = *(const float2*)(sS_wx + (size_t)s * DCH + 2 * lane);
    float aex = sS_w[s];
    __syncthreads();
    const float* es = e2 + w * 64;
    int pib0 = sb * 64;
    int n = b * 64 + (pib0 >> 9);
    int row0 = (pib0 & 511) + 2;
    const float* xp = x + ((size_t)b * LSEQ + pib0) * DCH + 2 * lane;
    unsigned short* pp = P + ((size_t)n * PH + row0) * DCH + 2 * lane;
    for (int j = 0; j < 64; ++j) {
        float e = es[j];
        aex += e;
        float2 xv = *(const float2*)xp;
        axx.x += e * xv.x;
        axx.y += e * xv.y;
        float inv = 1.f / aex;
        unsigned pk = ((unsigned)f2bf(axx.y * inv + xv.y) << 16) | f2bf(axx.x * inv + xv.x);
        *(unsigned*)pp = pk;
        xp += DCH;
        pp += DCH;
    }
}

// ---------------- Stage 6: conv as bf16 MFMA GEMM (128x128 tile, K=768) ----------------
// v3 (this round): the 6 kn neighbor-shifts are just ROW OFFSETS into the same
// 133-row P window — so stage the whole 144-row x 128-ch panel ONCE (36 KB, one
// barrier), then run all 12 K-steps barrier-free reading kn-shifted windows from
// the resident panel. Staging DMA drops 192->36 KB/wg (6x), barriers 14->2/wg.
// Swizzle: physical chunk (0..15) = (c&8) | ((c&7) ^ (gr&7)), applied at the DMA
// *source* (LDS dest stays linear, rule 21) and inverted on ds_read. A quarter-wave
// reads 16 consecutive rows -> chunk spread over 8 bank-groups x 2 lanes = free.
// B fragments stay register-direct from L2-resident W3 (double-buffered).
__global__ __launch_bounds__(256) void k_conv(const unsigned short* __restrict__ P,
                                              const unsigned short* __restrict__ W3,
                                              const float* __restrict__ conv_b,
                                              unsigned short* __restrict__ convout) {
    int n = blockIdx.x >> 2;
    int h0 = (blockIdx.x & 3) * 128;
    __shared__ __align__(16) char panel[144 * 256];   // 36864 B; epilogue reuses first 34816 B
    int t = threadIdx.x;
    int wave = t >> 6, lane = t & 63;
    f32x4 acc[4][4] = {};
    const unsigned short* Pn = P + (size_t)n * PH * DCH;
    int wm = (wave >> 1) * 64, wn = (wave & 1) * 64;
    int kchunk = lane >> 4;                   // 0..3 (MFMA k-slice group)
    int bcol = wn + (lane & 15);              // B out-channel base (+ni*16)

    bf16x8 breg[2][8];

    auto loadB = [&](int kt, bf16x8* dstB) {
        #pragma unroll
        for (int ks = 0; ks < 2; ++ks)
            #pragma unroll
            for (int ni = 0; ni < 4; ++ni)
                dstB[ks * 4 + ni] = *(const bf16x8*)(
                    W3 + (size_t)((kt * 2 + ks) * 4 + kchunk) * 1024 + (bcol + ni * 16) * 8);
    };

    // ---- stage the full panel: 9 rounds x (4 waves x 64 lanes x 16 B) = 144 rows ----
    {
        int c = lane & 15;                    // physical 16B-chunk within row
        #pragma unroll
        for (int j = 0; j < 9; ++j) {
            int r = j * 16 + wave * 4 + (lane >> 4);    // LDS row 0..143
            int gr = h0 + r;                             // global padded row
            int grc = min(gr, PH - 1);                   // clamp: rows >519 unread
            int srcc = (c & 8) | ((c & 7) ^ (gr & 7));   // source-side swizzle
            async_copy16(Pn + (size_t)grc * DCH + srcc * 8,
                         panel + j * 4096 + wave * 1024 + lane * 16);
        }
    }
    loadB(0, breg[0]);
    __syncthreads();                           // drains vmcnt(0): panel + breg[0] ready

    // ---- 12 K-steps, NO barriers: pure ds_read + MFMA on the resident panel ----
    #pragma unroll
    for (int kt = 0; kt < 12; ++kt) {
        if (kt < 11) loadB(kt + 1, breg[(kt + 1) & 1]);   // prefetch next B from L2
        int kn = kt >> 1;
        int cb = (kt & 1) * 8;                 // chunk-half: channels 0..63 / 64..127
        #pragma unroll
        for (int ks = 0; ks < 2; ++ks) {
            bf16x8 af[4];
            #pragma unroll
            for (int mi = 0; mi < 4; ++mi) {
                int row = wm + mi * 16 + (lane & 15) + kn;          // panel row
                int phys = cb + ((ks * 4 + kchunk) ^ ((h0 + row) & 7));
                af[mi] = *(const bf16x8*)(panel + row * 256 + phys * 16);
            }
            #pragma unroll
            for (int mi = 0; mi < 4; ++mi)
                #pragma unroll
                for (int ni = 0; ni < 4; ++ni)
                    acc[mi][ni] = __builtin_amdgcn_mfma_f32_16x16x32_bf16(af[mi],
                                                                          breg[kt & 1][ks * 4 + ni],
                                                                          acc[mi][ni], 0, 0, 0);
        }
    }
    __syncthreads();   // all panel reads complete before C-stage overwrite
    // C/D layout: col=lane&15, row=(lane>>4)*4+reg  [m89-verified]
    unsigned short* clds = (unsigned short*)panel;
    #pragma unroll
    for (int mi = 0; mi < 4; ++mi)
        #pragma unroll
        for (int ni = 0; ni < 4; ++ni) {
            int col = wn + ni * 16 + (lane & 15);
            float bias = conv_b[col];
            #pragma unroll
            for (int r = 0; r < 4; ++r) {
                int row = wm + mi * 16 + (lane >> 4) * 4 + r;
                clds[row * 136 + col] = f2bf(acc[mi][ni][r] + bias);
            }
        }
    __syncthreads();
    // coalesced store: 2048 granules of 16 B
    size_t base = (size_t)(n * 512 + h0) * DCH;
    #pragma unroll
    for (int it = 0; it < 8; ++it) {
        int idx = it * 256 + t;
        int row = idx >> 4, g = idx & 15;
        uint4 v = *(const uint4*)(clds + row * 136 + g * 8);
        *(uint4*)(convout + base + (size_t)row * DCH + g * 8) = v;
    }
}

// ---------------- Stage 7-9 fused tail: block_repr + a_s + a_o + fusion, one block per n ----
// All three old kernels (k_as, k_ao, k_fusion) had the same per-n chain; fusing keeps
// br/a_s/a_o in LDS (no HBM round-trip, no extra launches). LDS budget 39.4 KB
// -> 4 blocks/CU, same as old k_as. fu aliases sp tail (barrier-separated lifetime).
__global__ __launch_bounds__(256) void k_tail(const unsigned short* __restrict__ conv,
                                              const unsigned short* __restrict__ P,
                                              const float* __restrict__ fusion_w,
                                              const float* __restrict__ fusion_b,
                                              float* __restrict__ block_repr,
                                              float* __restrict__ out) {
    int n = blockIdx.x, t = threadIdx.x;
    int g = t & 15, rs = t >> 4;
    int b = n >> 6, c = n & 63;
    __shared__ __align__(16) float sp[512 * 17];   // partials / rp[16][130] / red / fu / comb
    __shared__ float s[512];
    __shared__ float br[128];
    __shared__ float as_l[128];
    __shared__ float ao_l[128];
    __shared__ float red[128];
    __shared__ int rb[128];
    float* rp = sp;                                 // [16][130] view
    const unsigned short* base = conv + (size_t)n * 512 * DCH;

    // ================= phase A: block_repr + a_s (from convout) =================
    // ---- A0: column max ----
    float m[8];
    #pragma unroll
    for (int e = 0; e < 8; ++e) m[e] = -INFINITY;
    for (int i = 0; i < 32; ++i) {
        int row = i * 16 + rs;
        uint4 v = *(const uint4*)(base + row * DCH + g * 8);
        unsigned vv[4] = {v.x, v.y, v.z, v.w};
        #pragma unroll
        for (int e = 0; e < 4; ++e) {
            m[2 * e]     = fmaxf(m[2 * e],     bf2f((unsigned short)(vv[e] & 0xffff)));
            m[2 * e + 1] = fmaxf(m[2 * e + 1], bf2f((unsigned short)(vv[e] >> 16)));
        }
    }
    #pragma unroll
    for (int e = 0; e < 8; ++e) rp[rs * 130 + g * 8 + e] = m[e];
    __syncthreads();
    if (t < 128) {
        float bm = rp[t];
        #pragma unroll
        for (int r2 = 1; r2 < 16; ++r2) bm = fmaxf(bm, rp[r2 * 130 + t]);
        br[t] = bm;
        block_repr[n * DCH + t] = bm;   // kept for debugging parity; cheap (256 KB)
    }
    __syncthreads();

    // ---- A1: scores s[row] = (conv[row] . br) * SCALE ----
    float brv[8];
    #pragma unroll
    for (int e = 0; e < 8; ++e) brv[e] = br[g * 8 + e];
    for (int i = 0; i < 32; ++i) {
        int row = i * 16 + rs;
        uint4 v = *(const uint4*)(base + row * DCH + g * 8);
        unsigned vv[4] = {v.x, v.y, v.z, v.w};
        float p = 0.f;
        #pragma unroll
        for (int e = 0; e < 4; ++e) {
            p += bf2f((unsigned short)(vv[e] & 0xffff)) * brv[2 * e];
            p += bf2f((unsigned short)(vv[e] >> 16))    * brv[2 * e + 1];
        }
        sp[row * 17 + g] = p;
    }
    __syncthreads();
    #pragma unroll
    for (int rr = 0; rr < 2; ++rr) {
        int row = t * 2 + rr;
        float p = 0.f;
        #pragma unroll
        for (int j = 0; j < 16; ++j) p += sp[row * 17 + j];
        s[row] = p * SCALE_F;
    }
    __syncthreads();

    // ---- A2: softmax over s[512] (scratch reuses sp after scores consumed) ----
    float* redA = sp;
    float mm = fmaxf(s[t], s[t + 256]);
    __syncthreads();          // all score reads of sp done before overwrite
    redA[t] = mm;
    __syncthreads();
    for (int off = 128; off > 0; off >>= 1) {
        if (t < off) redA[t] = fmaxf(redA[t], redA[t + off]);
        __syncthreads();
    }
    float smax = redA[0];
    __syncthreads();
    float e0 = expf(s[t] - smax), e1 = expf(s[t + 256] - smax);
    redA[t] = e0 + e1;
    __syncthreads();
    for (int off = 128; off > 0; off >>= 1) {
        if (t < off) redA[t] += redA[t + off];
        __syncthreads();
    }
    float inv = 1.f / redA[0];
    __syncthreads();
    s[t] = e0 * inv;
    s[t + 256] = e1 * inv;
    __syncthreads();

    // ---- A3: weighted sum -> a_s (stays in LDS) ----
    float acc[8];
    #pragma unroll
    for (int e = 0; e < 8; ++e) acc[e] = 0.f;
    for (int i = 0; i < 32; ++i) {
        int row = i * 16 + rs;
        float w = s[row];
        uint4 v = *(const uint4*)(base + row * DCH + g * 8);
        unsigned vv[4] = {v.x, v.y, v.z, v.w};
        #pragma unroll
        for (int e = 0; e < 4; ++e) {
            acc[2 * e]     += w * bf2f((unsigned short)(vv[e] & 0xffff));
            acc[2 * e + 1] += w * bf2f((unsigned short)(vv[e] >> 16));
        }
    }
    #pragma unroll
    for (int e = 0; e < 8; ++e) rp[rs * 130 + g * 8 + e] = acc[e];
    __syncthreads();
    if (t < 128) {
        float p = 0.f;
        #pragma unroll
        for (int r2 = 0; r2 < 16; ++r2) p += rp[r2 * 130 + t];
        as_l[t] = p;
    }

    // ================= phase B: a_o = attn(br, xbo, xbo) (from P) =================
    if (t < 128) {
        int pib = (c + 1) * 512 - 64 + t;       // window straddling block end
        pib = min(pib, LSEQ - 1);               // edge-clamp at sequence end
        int n2 = b * 64 + (pib >> 9);
        int row = (pib & 511) + 2;
        rb[t] = (n2 * PH + row) * DCH;
    }
    __syncthreads();                            // as_l published; rb ready; sp free
    #pragma unroll
    for (int r = 0; r < 8; ++r) {
        int row = rs * 8 + r;
        uint4 v = *(const uint4*)(P + rb[row] + g * 8);
        unsigned vv[4] = {v.x, v.y, v.z, v.w};
        float p = 0.f;
        #pragma unroll
        for (int e = 0; e < 4; ++e) {
            p += bf2f((unsigned short)(vv[e] & 0xffff)) * brv[2 * e];
            p += bf2f((unsigned short)(vv[e] >> 16))    * brv[2 * e + 1];
        }
        sp[row * 17 + g] = p;
    }
    __syncthreads();
    if (t < 128) {
        float p = 0.f;
        #pragma unroll
        for (int j = 0; j < 16; ++j) p += sp[t * 17 + j];
        s[t] = p * SCALE_F;
        red[t] = s[t];
    }
    __syncthreads();
    for (int off = 64; off > 0; off >>= 1) {
        if (t < off) red[t] = fmaxf(red[t], red[t + off]);
        __syncthreads();
    }
    float smaxB = red[0];
    __syncthreads();
    if (t < 128) {
        float e = expf(s[t] - smaxB);
        s[t] = e;
        red[t] = e;
    }
    __syncthreads();
    for (int off = 64; off > 0; off >>= 1) {
        if (t < off) red[t] += red[t + off];
        __syncthreads();
    }
    float invB = 1.f / red[0];
    __syncthreads();
    if (t < 128) s[t] *= invB;
    __syncthreads();
    float accB[8];
    #pragma unroll
    for (int e = 0; e < 8; ++e) accB[e] = 0.f;
    #pragma unroll
    for (int r = 0; r < 8; ++r) {
        int row = rs * 8 + r;
        float w = s[row];
        uint4 v = *(const uint4*)(P + rb[row] + g * 8);
        unsigned vv[4] = {v.x, v.y, v.z, v.w};
        #pragma unroll
        for (int e = 0; e < 4; ++e) {
            accB[2 * e]     += w * bf2f((unsigned short)(vv[e] & 0xffff));
            accB[2 * e + 1] += w * bf2f((unsigned short)(vv[e] >> 16));
        }
    }
    #pragma unroll
    for (int e = 0; e < 8; ++e) sp[rs * 130 + g * 8 + e] = accB[e];
    __syncthreads();
    if (t < 128) {
        float p = 0.f;
        #pragma unroll
        for (int r2 = 0; r2 < 16; ++r2) p += sp[r2 * 130 + t];
        ao_l[t] = p;
    }
    __syncthreads();

    // ================= phase C: out = concat(a_s,a_o,br) @ fusion_w + b =================
    float* fu = sp + 8320;                      // 384 floats, disjoint from comb region
    if (t < 128) {
        fu[t] = as_l[t];
        fu[128 + t] = ao_l[t];
        fu[256 + t] = br[t];
    }
    __syncthreads();
    {
        int col = t & 127, h = t >> 7;          // 2 threads per output column
        float a2 = (h == 0) ? fusion_b[col] : 0.f;
        for (int j = h * 192; j < h * 192 + 192; ++j)
            a2 += fu[j] * fusion_w[j * DCH + col];
        sp[h * 128 + col] = a2;
    }
    __syncthreads();
    if (t < 128) {
        float v = sp[t] + sp[128 + t];
        out[n * DCH + t] = v;
        out[NB * 64 * DCH + n * DCH + t] = v;   // second tuple element (out, out)
    }
}

extern "C" void kernel_launch(void* const* d_in, const int* in_sizes, int n_in,
                              void* d_out, int out_size, void* d_ws, size_t ws_size,
                              hipStream_t stream) {
    const float* x        = (const float*)d_in[0];
    const float* w_lw     = (const float*)d_in[1];
    const float* b_lw     = (const float*)d_in[2];
    const float* conv_w   = (const float*)d_in[3];
    const float* conv_b   = (const float*)d_in[4];
    const float* fusion_w = (const float*)d_in[5];
    const float* fusion_b = (const float*)d_in[6];
    float* out = (float*)d_out;

    char* ws = (char*)d_ws;
    size_t off = 0;
    auto alloc = [&](size_t bytes) { char* p = ws + off; off += (bytes + 255) & ~(size_t)255; return p; };
    float* logits     = (float*)alloc(NB * LSEQ * 4);
    float* exg        = (float*)alloc(NB * LSEQ * 4);
    float* subM       = (float*)alloc(NSUB * 4);
    float* seedM      = (float*)alloc(NSUB * 4);
    float* S_w        = (float*)alloc(NSUB * 4);
    float* sS_w       = (float*)alloc(NSUB * 4);
    float* S_wx       = (float*)alloc((size_t)NSUB * DCH * 4);
    float* sS_wx      = (float*)alloc((size_t)NSUB * DCH * 4);
    float* block_repr = (float*)alloc(NBLK * DCH * 4);
    unsigned short* W3      = (unsigned short*)alloc(128 * 768 * 2);
    unsigned short* P       = (unsigned short*)alloc((size_t)NBLK * PH * DCH * 2);
    unsigned short* convout = (unsigned short*)alloc((size_t)NBLK * 512 * DCH * 2);

    k_init<<<NBLK, 256, 0, stream>>>(conv_w, W3, P);
    k_logits2<<<NCHUNK, 256, 0, stream>>>(x, w_lw, b_lw, logits, subM);
    k_seed_max2<<<NB, 64, 0, stream>>>(subM, seedM);
    k_sums<<<NCHUNK, 256, 0, stream>>>(x, logits, seedM, exg, S_w, S_wx);
    k_seed_w<<<NB, 64, 0, stream>>>(S_w, sS_w);
    k_seed_sums2<<<NB * 8, 256, 0, stream>>>(S_wx, sS_wx);
    k_apply<<<NSUB / 2, 128, 0, stream>>>(x, exg, sS_w, sS_wx, P);
    k_conv<<<NBLK * 4, 256, 0, stream>>>(P, W3, conv_b, convout);
    k_tail<<<NBLK, 256, 0, stream>>>(convout, P, fusion_w, fusion_b, block_repr, out);
}

// Round 6
// 349.857 us; speedup vs baseline: 1.1058x; 1.0100x over previous
//
#include <hip/hip_runtime.h>
#include <hip/hip_bf16.h>
#include <hip/hip_cooperative_groups.h>

namespace cg = cooperative_groups;

// Problem constants (reference: D=128, BC=64, BS=512, K=6, OV=128, B=8)
#define NB 8            // batches
#define LSEQ 32768      // BC*BS positions per batch
#define DCH 128         // channels
#define NCHUNK 1024     // 256-row chunks
#define NSUB 4096       // 64-row sub-chunks
#define NBLK 512        // B*BC conv blocks
#define PH 520          // padded rows per block (2 front + 512 + pad, rounded)
#define SCALE_F 0.08838834764831845f

typedef __bf16 bf16x8 __attribute__((ext_vector_type(8)));
typedef float f32x4 __attribute__((ext_vector_type(4)));

__device__ __forceinline__ float bf2f(unsigned short u) {
    return __uint_as_float(((unsigned)u) << 16);
}
__device__ __forceinline__ unsigned short f2bf(float f) {
    unsigned u = __float_as_uint(f);
    u += 0x7fffu + ((u >> 16) & 1u);   // round-to-nearest-even
    return (unsigned short)(u >> 16);
}

// async global->LDS DMA, 16 B per lane; LDS dest = wave-uniform base + lane*16
__device__ __forceinline__ void async_copy16(const void* gsrc, void* ldst) {
    __builtin_amdgcn_global_load_lds(
        (const __attribute__((address_space(1))) unsigned int*)gsrc,
        (__attribute__((address_space(3))) unsigned int*)ldst, 16, 0, 0);
}

// ================== k_front: cooperative fused front half ==================
// Phase A: logits = silu(x @ w_lw + b) (kept in LDS wper) + per-sub max -> subM
// Phase B: exclusive prefix-MAX over 512 subs/batch (blocks 0..7)
// Phase C: w_i = exp(l - max(seedM, cummax)) via 64-lane shfl prefix-max
//          (bit-exact vs serial: max associative, identical expf inputs);
//          per-sub S_w + column-parallel S_wx
// Phase D: exclusive prefix-SUM scans of S_w (blocks 0..7) and S_wx (blocks 8..71)
// Phase E: apply scan -> prefix_x, write bf16 padded P (wave per sub, w from wper)
// logits/exg globals are gone: the SAME block owns chunk c in A, C and E.
__global__ __launch_bounds__(256, 4) void k_front(const float* __restrict__ x,
                                                  const float* __restrict__ w_lw,
                                                  const float* __restrict__ b_lw,
                                                  float* __restrict__ subM,
                                                  float* __restrict__ seedM,
                                                  float* __restrict__ S_w,
                                                  float* __restrict__ sS_w,
                                                  float* __restrict__ S_wx,
                                                  float* __restrict__ sS_wx,
                                                  unsigned short* __restrict__ P) {
    cg::grid_group grid = cg::this_grid();
    int chunk = blockIdx.x, t = threadIdx.x;
    int g = t & 15, rs = t >> 4;
    __shared__ float sp[256 * 17];     // scratch: partials / rp[16][130] / tots
    __shared__ float red[256];
    __shared__ float wper[256];        // persistent: logits (A->C), then w (C->E)

    // ---------------- phase A: logits ----------------
    {
        float wv[8];
        #pragma unroll
        for (int e = 0; e < 8; ++e) wv[e] = w_lw[g * 8 + e];
        float bb = b_lw[0];
        size_t base = (size_t)chunk * 256 * DCH;
        for (int i = 0; i < 16; ++i) {
            int row = rs * 16 + i;
            float4 a  = *(const float4*)(x + base + (size_t)row * DCH + g * 8);
            float4 b4 = *(const float4*)(x + base + (size_t)row * DCH + g * 8 + 4);
            sp[row * 17 + g] = a.x * wv[0] + a.y * wv[1] + a.z * wv[2] + a.w * wv[3] +
                               b4.x * wv[4] + b4.y * wv[5] + b4.z * wv[6] + b4.w * wv[7];
        }
        __syncthreads();
        float s = bb;
        #pragma unroll
        for (int j = 0; j < 16; ++j) s += sp[t * 17 + j];
        float l = s / (1.f + expf(-s));          // silu
        wper[t] = l;
        red[t] = l;
        __syncthreads();
        for (int off = 32; off >= 1; off >>= 1) {
            if ((t & 63) < off) red[t] = fmaxf(red[t], red[t + off]);
            __syncthreads();
        }
        if ((t & 63) == 0) subM[chunk * 4 + (t >> 6)] = red[t];
    }
    grid.sync();

    // ---------------- phase B: prefix-MAX over subs (blocks 0..7, wave 0) ----------------
    if (chunk < 8 && t < 64) {
        const float* src = subM + chunk * 512;
        float* dst = seedM + chunk * 512;
        float v[8];
        float m = -INFINITY;
        #pragma unroll
        for (int j = 0; j < 8; ++j) { v[j] = src[t * 8 + j]; m = fmaxf(m, v[j]); }
        float incl = m;
        #pragma unroll
        for (int off = 1; off < 64; off <<= 1) {
            float o = __shfl_up(incl, off, 64);
            if (t >= off) incl = fmaxf(incl, o);
        }
        float ex = __shfl_up(incl, 1, 64);
        if (t == 0) ex = -INFINITY;
        float run = ex;
        #pragma unroll
        for (int j = 0; j < 8; ++j) { dst[t * 8 + j] = run; run = fmaxf(run, v[j]); }
    }
    grid.sync();

    // ---------------- phase C: weights + per-sub sums ----------------
    {
        int w = t >> 6, lane = t & 63;
        float l = wper[t];                       // own slot only
        float M = seedM[chunk * 4 + w];
        float incl = l;                          // inclusive prefix-max within sub
        #pragma unroll
        for (int off = 1; off < 64; off <<= 1) {
            float o = __shfl_up(incl, off, 64);
            if (lane >= off) incl = fmaxf(incl, o);
        }
        float w_t = expf(l - fmaxf(M, incl));
        wper[t] = w_t;                           // own slot; cross-reads after sync below
        red[t] = w_t;
        __syncthreads();
        for (int off = 32; off >= 1; off >>= 1) {
            if ((t & 63) < off) red[t] += red[t + off];
            __syncthreads();
        }
        if ((t & 63) == 0) S_w[chunk * 4 + (t >> 6)] = red[t];
        // column-parallel S_wx: thread (g,rs) covers rows rs*16..+15
        float acc[8];
        #pragma unroll
        for (int e = 0; e < 8; ++e) acc[e] = 0.f;
        size_t base = (size_t)chunk * 256 * DCH;
        for (int i = 0; i < 16; ++i) {
            int row = rs * 16 + i;
            float ww = wper[row];
            float4 a  = *(const float4*)(x + base + (size_t)row * DCH + g * 8);
            float4 b4 = *(const float4*)(x + base + (size_t)row * DCH + g * 8 + 4);
            acc[0] += ww * a.x;  acc[1] += ww * a.y;  acc[2] += ww * a.z;  acc[3] += ww * a.w;
            acc[4] += ww * b4.x; acc[5] += ww * b4.y; acc[6] += ww * b4.z; acc[7] += ww * b4.w;
        }
        float* rp = sp;                          // [16][130] view
        #pragma unroll
        for (int e = 0; e < 8; ++e) rp[rs * 130 + g * 8 + e] = acc[e];
        __syncthreads();
        #pragma unroll
        for (int k = 0; k < 2; ++k) {
            int idx = k * 256 + t;               // 4 subs x 128 ch
            int sub = idx >> 7, c = idx & 127;
            float sm = rp[(sub * 4 + 0) * 130 + c] + rp[(sub * 4 + 1) * 130 + c] +
                       rp[(sub * 4 + 2) * 130 + c] + rp[(sub * 4 + 3) * 130 + c];
            S_wx[((size_t)chunk * 4 + sub) * DCH + c] = sm;
        }
    }
    grid.sync();

    // ---------------- phase D: seed scans (S_w: blocks 0..7; S_wx: blocks 8..71) ----------------
    if (chunk < 8) {
        if (t < 64) {
            const float* src = S_w + chunk * 512;
            float* dst = sS_w + chunk * 512;
            float v[8];
            float tot = 0.f;
            #pragma unroll
            for (int j = 0; j < 8; ++j) { v[j] = src[t * 8 + j]; tot += v[j]; }
            float incl = tot;
            #pragma unroll
            for (int off = 1; off < 64; off <<= 1) {
                float o = __shfl_up(incl, off, 64);
                if (t >= off) incl += o;
            }
            float ex = __shfl_up(incl, 1, 64);
            if (t == 0) ex = 0.f;
            float run = ex;
            #pragma unroll
            for (int j = 0; j < 8; ++j) { dst[t * 8 + j] = run; run += v[j]; }
        }
    } else if (chunk < 72) {
        int b = (chunk - 8) >> 3, cgx = (chunk - 8) & 7;
        int cl = t & 15, seg = t >> 4;
        int c = cgx * 16 + cl;
        float* tots = sp;                        // [16][17] view
        const float* src = S_wx + (size_t)b * 512 * DCH + c;
        float* dst = sS_wx + (size_t)b * 512 * DCH + c;
        int s0 = seg * 32;
        float tot = 0.f;
        for (int j = 0; j < 32; ++j) tot += src[(size_t)(s0 + j) * DCH];
        tots[seg * 17 + cl] = tot;
        __syncthreads();
        if (t < 16) {
            float run = 0.f;
            for (int s2 = 0; s2 < 16; ++s2) { float tmp = tots[s2 * 17 + t]; tots[s2 * 17 + t] = run; run += tmp; }
        }
        __syncthreads();
        float run = tots[seg * 17 + cl];
        for (int j = 0; j < 32; ++j) {
            float val = src[(size_t)(s0 + j) * DCH];
            dst[(size_t)(s0 + j) * DCH] = run;
            run += val;
        }
    }
    grid.sync();

    // ---------------- phase E: apply scan -> P (wave per sub, w from wper) ----------------
    {
        int w = t >> 6, lane = t & 63;
        int s = chunk * 4 + w;                   // sub-chunk id 0..4095
        int b = s >> 9, sb = s & 511;
        float2 axx = *(const float2*)(sS_wx + (size_t)s * DCH + 2 * lane);
        float aex = sS_w[s];
        const float* es = wper + w * 64;         // this chunk's w values (phase C)
        int pib0 = sb * 64;
        int n = b * 64 + (pib0 >> 9);
        int row0 = (pib0 & 511) + 2;
        const float* xp = x + ((size_t)b * LSEQ + pib0) * DCH + 2 * lane;
        unsigned short* pp = P + ((size_t)n * PH + row0) * DCH + 2 * lane;
        for (int j = 0; j < 64; ++j) {
            float e = es[j];
            aex += e;
            float2 xv = *(const float2*)xp;
            axx.x += e * xv.x;
            axx.y += e * xv.y;
            float inv = 1.f / aex;
            unsigned pk = ((unsigned)f2bf(axx.y * inv + xv.y) << 16) | f2bf(axx.x * inv + xv.x);
            *(unsigned*)pp = pk;
            xp += DCH;
            pp += DCH;
        }
    }
}

// ================== fallback chain (R4 kernels, used only if coop not guaranteed) ==================
__global__ __launch_bounds__(256) void k_logits2(const float* __restrict__ x,
                                                 const float* __restrict__ w_lw,
                                                 const float* __restrict__ b_lw,
                                                 float* __restrict__ logits,
                                                 float* __restrict__ subM) {
    int chunk = blockIdx.x, t = threadIdx.x;
    int g = t & 15, rs = t >> 4;
    __shared__ float sp[256 * 17];
    __shared__ float red[256];
    float wv[8];
    #pragma unroll
    for (int e = 0; e < 8; ++e) wv[e] = w_lw[g * 8 + e];
    float bb = b_lw[0];
    size_t base = (size_t)chunk * 256 * DCH;
    for (int i = 0; i < 16; ++i) {
        int row = rs * 16 + i;
        float4 a  = *(const float4*)(x + base + (size_t)row * DCH + g * 8);
        float4 b4 = *(const float4*)(x + base + (size_t)row * DCH + g * 8 + 4);
        sp[row * 17 + g] = a.x * wv[0] + a.y * wv[1] + a.z * wv[2] + a.w * wv[3] +
                           b4.x * wv[4] + b4.y * wv[5] + b4.z * wv[6] + b4.w * wv[7];
    }
    __syncthreads();
    float s = bb;
    #pragma unroll
    for (int j = 0; j < 16; ++j) s += sp[t * 17 + j];
    float l = s / (1.f + expf(-s));
    logits[(size_t)chunk * 256 + t] = l;
    red[t] = l;
    __syncthreads();
    for (int off = 32; off >= 1; off >>= 1) {
        if ((t & 63) < off) red[t] = fmaxf(red[t], red[t + off]);
        __syncthreads();
    }
    if ((t & 63) == 0) subM[chunk * 4 + (t >> 6)] = red[t];
}

__global__ __launch_bounds__(64) void k_seed_max2(const float* __restrict__ subM,
                                                  float* __restrict__ seedM) {
    int b = blockIdx.x, lane = threadIdx.x;
    const float* src = subM + b * 512;
    float* dst = seedM + b * 512;
    float v[8];
    float m = -INFINITY;
    #pragma unroll
    for (int j = 0; j < 8; ++j) { v[j] = src[lane * 8 + j]; m = fmaxf(m, v[j]); }
    float incl = m;
    #pragma unroll
    for (int off = 1; off < 64; off <<= 1) {
        float o = __shfl_up(incl, off, 64);
        if (lane >= off) incl = fmaxf(incl, o);
    }
    float ex = __shfl_up(incl, 1, 64);
    if (lane == 0) ex = -INFINITY;
    float run = ex;
    #pragma unroll
    for (int j = 0; j < 8; ++j) { dst[lane * 8 + j] = run; run = fmaxf(run, v[j]); }
}

__global__ __launch_bounds__(256) void k_sums(const float* __restrict__ x,
                                              const float* __restrict__ logits,
                                              const float* __restrict__ seedM,
                                              float* __restrict__ exg,
                                              float* __restrict__ S_w,
                                              float* __restrict__ S_wx) {
    int chunk = blockIdx.x, t = threadIdx.x;
    int g = t & 15, rs = t >> 4;
    __shared__ float llog[256];
    __shared__ float wbuf[256];
    __shared__ float red[256];
    __shared__ float rp[16 * 130];
    llog[t] = logits[(size_t)chunk * 256 + t];
    __syncthreads();
    if (t < 4) {
        float M = seedM[chunk * 4 + t];
        float m = -INFINITY;
        for (int i = 0; i < 64; ++i) {
            float l = llog[t * 64 + i];
            m = fmaxf(m, l);
            wbuf[t * 64 + i] = expf(l - fmaxf(M, m));
        }
    }
    __syncthreads();
    float w_t = wbuf[t];
    exg[(size_t)chunk * 256 + t] = w_t;
    red[t] = w_t;
    __syncthreads();
    for (int off = 32; off >= 1; off >>= 1) {
        if ((t & 63) < off) red[t] += red[t + off];
        __syncthreads();
    }
    if ((t & 63) == 0) S_w[chunk * 4 + (t >> 6)] = red[t];
    float acc[8];
    #pragma unroll
    for (int e = 0; e < 8; ++e) acc[e] = 0.f;
    size_t base = (size_t)chunk * 256 * DCH;
    for (int i = 0; i < 16; ++i) {
        int row = rs * 16 + i;
        float w = wbuf[row];
        float4 a  = *(const float4*)(x + base + (size_t)row * DCH + g * 8);
        float4 b4 = *(const float4*)(x + base + (size_t)row * DCH + g * 8 + 4);
        acc[0] += w * a.x;  acc[1] += w * a.y;  acc[2] += w * a.z;  acc[3] += w * a.w;
        acc[4] += w * b4.x; acc[5] += w * b4.y; acc[6] += w * b4.z; acc[7] += w * b4.w;
    }
    #pragma unroll
    for (int e = 0; e < 8; ++e) rp[rs * 130 + g * 8 + e] = acc[e];
    __syncthreads();
    #pragma unroll
    for (int k = 0; k < 2; ++k) {
        int idx = k * 256 + t;
        int sub = idx >> 7, c = idx & 127;
        float sm = rp[(sub * 4 + 0) * 130 + c] + rp[(sub * 4 + 1) * 130 + c] +
                   rp[(sub * 4 + 2) * 130 + c] + rp[(sub * 4 + 3) * 130 + c];
        S_wx[((size_t)chunk * 4 + sub) * DCH + c] = sm;
    }
}

__global__ __launch_bounds__(64) void k_seed_w(const float* __restrict__ S_w,
                                               float* __restrict__ sS_w) {
    int b = blockIdx.x, lane = threadIdx.x;
    const float* src = S_w + b * 512;
    float* dst = sS_w + b * 512;
    float v[8];
    float tot = 0.f;
    #pragma unroll
    for (int j = 0; j < 8; ++j) { v[j] = src[lane * 8 + j]; tot += v[j]; }
    float incl = tot;
    #pragma unroll
    for (int off = 1; off < 64; off <<= 1) {
        float o = __shfl_up(incl, off, 64);
        if (lane >= off) incl += o;
    }
    float ex = __shfl_up(incl, 1, 64);
    if (lane == 0) ex = 0.f;
    float run = ex;
    #pragma unroll
    for (int j = 0; j < 8; ++j) { dst[lane * 8 + j] = run; run += v[j]; }
}

__global__ __launch_bounds__(256) void k_seed_sums2(const float* __restrict__ S_wx,
                                                    float* __restrict__ sS_wx) {
    int b = blockIdx.x >> 3, cgx = blockIdx.x & 7;
    int t = threadIdx.x;
    int cl = t & 15, seg = t >> 4;
    int c = cgx * 16 + cl;
    __shared__ float tots[16][17];
    const float* src = S_wx + (size_t)b * 512 * DCH + c;
    float* dst = sS_wx + (size_t)b * 512 * DCH + c;
    int s0 = seg * 32;
    float tot = 0.f;
    for (int j = 0; j < 32; ++j) tot += src[(size_t)(s0 + j) * DCH];
    tots[seg][cl] = tot;
    __syncthreads();
    if (t < 16) {
        float run = 0.f;
        for (int s = 0; s < 16; ++s) { float tmp = tots[s][t]; tots[s][t] = run; run += tmp; }
    }
    __syncthreads();
    float run = tots[seg][cl];
    for (int j = 0; j < 32; ++j) {
        float val = src[(size_t)(s0 + j) * DCH];
        dst[(size_t)(s0 + j) * DCH] = run;
        run += val;
    }
}

__global__ __launch_bounds__(128) void k_apply(const float* __restrict__ x,
                                               const float* __restrict__ exg,
                                               const float* __restrict__ sS_w,
                                               const float* __restrict__ sS_wx,
                                               unsigned short* __restrict__ P) {
    int t = threadIdx.x, w = t >> 6, lane = t & 63;
    int s = blockIdx.x * 2 + w;
    int b = s >> 9, sb = s & 511;
    __shared__ float e2[128];
    e2[t] = exg[(size_t)blockIdx.x * 128 + t];
    float2 axx = *(const float2*)(sS_wx + (size_t)s * DCH + 2 * lane);
    float aex = sS_w[s];
    __syncthreads();
    const float* es = e2 + w * 64;
    int pib0 = sb * 64;
    int n = b * 64 + (pib0 >> 9);
    int row0 = (pib0 & 511) + 2;
    const float* xp = x + ((size_t)b * LSEQ + pib0) * DCH + 2 * lane;
    unsigned short* pp = P + ((size_t)n * PH + row0) * DCH + 2 * lane;
    for (int j = 0; j < 64; ++j) {
        float e = es[j];
        aex += e;
        float2 xv = *(const float2*)xp;
        axx.x += e * xv.x;
        axx.y += e * xv.y;
        float inv = 1.f / aex;
        unsigned pk = ((unsigned)f2bf(axx.y * inv + xv.y) << 16) | f2bf(axx.x * inv + xv.x);
        *(unsigned*)pp = pk;
        xp += DCH;
        pp += DCH;
    }
}

// ---------------- merged init: zero halo rows of P + weight repack W3 ----------------
// W3 flat index f = (((kt*2+ks)*4 + kchunk)*128 + o)*8 + e
//   maps to conv_w[o][ i ][ kn ],  i = (kt&1)*64 + (ks*4+kchunk)*8 + e,  kn = kt>>1.
__global__ __launch_bounds__(256) void k_init(const float* __restrict__ conv_w,
                                              unsigned short* __restrict__ W3,
                                              unsigned short* __restrict__ P) {
    int n = blockIdx.x, t = threadIdx.x;
    for (int i = t; i < 1024; i += 256) {
        int rr = i >> 7;                       // 0..7
        int row = (rr < 2) ? rr : 512 + rr;    // rows 0,1,514..519
        P[(n * PH + row) * DCH + (i & 127)] = 0;
    }
    int idx = n * 256 + t;                     // blocks 0..383 cover 98304 elems
    if (idx < 98304) {
        int e  = idx & 7;
        int o  = (idx >> 3) & 127;
        int kc = (idx >> 10) & 3;
        int kt2 = idx >> 12;                   // 0..23 = kt*2+ks
        int kt = kt2 >> 1, ks = kt2 & 1;
        int i  = (kt & 1) * 64 + (ks * 4 + kc) * 8 + e;
        int kn = kt >> 1;
        W3[idx] = f2bf(conv_w[(o * 128 + i) * 6 + kn]);
    }
}

// ---------------- Stage 6: conv as bf16 MFMA GEMM (128x128 tile, K=768) ----------------
// Panel staged ONCE (144 rows x 128 ch, 36 KB, one barrier); 12 K-steps barrier-free
// reading kn-shifted windows. Swizzle: physical chunk = (c&8) | ((c&7) ^ (gr&7)) at
// the DMA *source* (LDS dest linear, rule 21), inverted on ds_read. B register-direct
// from L2-resident W3 (double-buffered).
__global__ __launch_bounds__(256) void k_conv(const unsigned short* __restrict__ P,
                                              const unsigned short* __restrict__ W3,
                                              const float* __restrict__ conv_b,
                                              unsigned short* __restrict__ convout) {
    int n = blockIdx.x >> 2;
    int h0 = (blockIdx.x & 3) * 128;
    __shared__ __align__(16) char panel[144 * 256];   // 36864 B; epilogue reuses first 34816 B
    int t = threadIdx.x;
    int wave = t >> 6, lane = t & 63;
    f32x4 acc[4][4] = {};
    const unsigned short* Pn = P + (size_t)n * PH * DCH;
    int wm = (wave >> 1) * 64, wn = (wave & 1) * 64;
    int kchunk = lane >> 4;                   // 0..3 (MFMA k-slice group)
    int bcol = wn + (lane & 15);              // B out-channel base (+ni*16)

    bf16x8 breg[2][8];

    auto loadB = [&](int kt, bf16x8* dstB) {
        #pragma unroll
        for (int ks = 0; ks < 2; ++ks)
            #pragma unroll
            for (int ni = 0; ni < 4; ++ni)
                dstB[ks * 4 + ni] = *(const bf16x8*)(
                    W3 + (size_t)((kt * 2 + ks) * 4 + kchunk) * 1024 + (bcol + ni * 16) * 8);
    };

    // ---- stage the full panel: 9 rounds x (4 waves x 64 lanes x 16 B) = 144 rows ----
    {
        int c = lane & 15;                    // physical 16B-chunk within row
        #pragma unroll
        for (int j = 0; j < 9; ++j) {
            int r = j * 16 + wave * 4 + (lane >> 4);    // LDS row 0..143
            int gr = h0 + r;                             // global padded row
            int grc = min(gr, PH - 1);                   // clamp: rows >519 unread
            int srcc = (c & 8) | ((c & 7) ^ (gr & 7));   // source-side swizzle
            async_copy16(Pn + (size_t)grc * DCH + srcc * 8,
                         panel + j * 4096 + wave * 1024 + lane * 16);
        }
    }
    loadB(0, breg[0]);
    __syncthreads();                           // drains vmcnt(0): panel + breg[0] ready

    // ---- 12 K-steps, NO barriers: pure ds_read + MFMA on the resident panel ----
    #pragma unroll
    for (int kt = 0; kt < 12; ++kt) {
        if (kt < 11) loadB(kt + 1, breg[(kt + 1) & 1]);   // prefetch next B from L2
        int kn = kt >> 1;
        int cb = (kt & 1) * 8;                 // chunk-half: channels 0..63 / 64..127
        #pragma unroll
        for (int ks = 0; ks < 2; ++ks) {
            bf16x8 af[4];
            #pragma unroll
            for (int mi = 0; mi < 4; ++mi) {
                int row = wm + mi * 16 + (lane & 15) + kn;          // panel row
                int phys = cb + ((ks * 4 + kchunk) ^ ((h0 + row) & 7));
                af[mi] = *(const bf16x8*)(panel + row * 256 + phys * 16);
            }
            #pragma unroll
            for (int mi = 0; mi < 4; ++mi)
                #pragma unroll
                for (int ni = 0; ni < 4; ++ni)
                    acc[mi][ni] = __builtin_amdgcn_mfma_f32_16x16x32_bf16(af[mi],
                                                                          breg[kt & 1][ks * 4 + ni],
                                                                          acc[mi][ni], 0, 0, 0);
        }
    }
    __syncthreads();   // all panel reads complete before C-stage overwrite
    // C/D layout: col=lane&15, row=(lane>>4)*4+reg  [m89-verified]
    unsigned short* clds = (unsigned short*)panel;
    #pragma unroll
    for (int mi = 0; mi < 4; ++mi)
        #pragma unroll
        for (int ni = 0; ni < 4; ++ni) {
            int col = wn + ni * 16 + (lane & 15);
            float bias = conv_b[col];
            #pragma unroll
            for (int r = 0; r < 4; ++r) {
                int row = wm + mi * 16 + (lane >> 4) * 4 + r;
                clds[row * 136 + col] = f2bf(acc[mi][ni][r] + bias);
            }
        }
    __syncthreads();
    // coalesced store: 2048 granules of 16 B
    size_t base = (size_t)(n * 512 + h0) * DCH;
    #pragma unroll
    for (int it = 0; it < 8; ++it) {
        int idx = it * 256 + t;
        int row = idx >> 4, g = idx & 15;
        uint4 v = *(const uint4*)(clds + row * 136 + g * 8);
        *(uint4*)(convout + base + (size_t)row * DCH + g * 8) = v;
    }
}

// ---------------- Stage 7-9 fused tail: block_repr + a_s + a_o + fusion, one block per n ----
__global__ __launch_bounds__(256) void k_tail(const unsigned short* __restrict__ conv,
                                              const unsigned short* __restrict__ P,
                                              const float* __restrict__ fusion_w,
                                              const float* __restrict__ fusion_b,
                                              float* __restrict__ block_repr,
                                              float* __restrict__ out) {
    int n = blockIdx.x, t = threadIdx.x;
    int g = t & 15, rs = t >> 4;
    int b = n >> 6, c = n & 63;
    __shared__ __align__(16) float sp[512 * 17];   // partials / rp[16][130] / red / fu / comb
    __shared__ float s[512];
    __shared__ float br[128];
    __shared__ float as_l[128];
    __shared__ float ao_l[128];
    __shared__ float red[128];
    __shared__ int rb[128];
    float* rp = sp;                                 // [16][130] view
    const unsigned short* base = conv + (size_t)n * 512 * DCH;

    // ================= phase A: block_repr + a_s (from convout) =================
    float m[8];
    #pragma unroll
    for (int e = 0; e < 8; ++e) m[e] = -INFINITY;
    for (int i = 0; i < 32; ++i) {
        int row = i * 16 + rs;
        uint4 v = *(const uint4*)(base + row * DCH + g * 8);
        unsigned vv[4] = {v.x, v.y, v.z, v.w};
        #pragma unroll
        for (int e = 0; e < 4; ++e) {
            m[2 * e]     = fmaxf(m[2 * e],     bf2f((unsigned short)(vv[e] & 0xffff)));
            m[2 * e + 1] = fmaxf(m[2 * e + 1], bf2f((unsigned short)(vv[e] >> 16)));
        }
    }
    #pragma unroll
    for (int e = 0; e < 8; ++e) rp[rs * 130 + g * 8 + e] = m[e];
    __syncthreads();
    if (t < 128) {
        float bm = rp[t];
        #pragma unroll
        for (int r2 = 1; r2 < 16; ++r2) bm = fmaxf(bm, rp[r2 * 130 + t]);
        br[t] = bm;
        block_repr[n * DCH + t] = bm;
    }
    __syncthreads();

    float brv[8];
    #pragma unroll
    for (int e = 0; e < 8; ++e) brv[e] = br[g * 8 + e];
    for (int i = 0; i < 32; ++i) {
        int row = i * 16 + rs;
        uint4 v = *(const uint4*)(base + row * DCH + g * 8);
        unsigned vv[4] = {v.x, v.y, v.z, v.w};
        float p = 0.f;
        #pragma unroll
        for (int e = 0; e < 4; ++e) {
            p += bf2f((unsigned short)(vv[e] & 0xffff)) * brv[2 * e];
            p += bf2f((unsigned short)(vv[e] >> 16))    * brv[2 * e + 1];
        }
        sp[row * 17 + g] = p;
    }
    __syncthreads();
    #pragma unroll
    for (int rr = 0; rr < 2; ++rr) {
        int row = t * 2 + rr;
        float p = 0.f;
        #pragma unroll
        for (int j = 0; j < 16; ++j) p += sp[row * 17 + j];
        s[row] = p * SCALE_F;
    }
    __syncthreads();

    float* redA = sp;
    float mm = fmaxf(s[t], s[t + 256]);
    __syncthreads();
    redA[t] = mm;
    __syncthreads();
    for (int off = 128; off > 0; off >>= 1) {
        if (t < off) redA[t] = fmaxf(redA[t], redA[t + off]);
        __syncthreads();
    }
    float smax = redA[0];
    __syncthreads();
    float e0 = expf(s[t] - smax), e1 = expf(s[t + 256] - smax);
    redA[t] = e0 + e1;
    __syncthreads();
    for (int off = 128; off > 0; off >>= 1) {
        if (t < off) redA[t] += redA[t + off];
        __syncthreads();
    }
    float inv = 1.f / redA[0];
    __syncthreads();
    s[t] = e0 * inv;
    s[t + 256] = e1 * inv;
    __syncthreads();

    float acc[8];
    #pragma unroll
    for (int e = 0; e < 8; ++e) acc[e] = 0.f;
    for (int i = 0; i < 32; ++i) {
        int row = i * 16 + rs;
        float w = s[row];
        uint4 v = *(const uint4*)(base + row * DCH + g * 8);
        unsigned vv[4] = {v.x, v.y, v.z, v.w};
        #pragma unroll
        for (int e = 0; e < 4; ++e) {
            acc[2 * e]     += w * bf2f((unsigned short)(vv[e] & 0xffff));
            acc[2 * e + 1] += w * bf2f((unsigned short)(vv[e] >> 16));
        }
    }
    #pragma unroll
    for (int e = 0; e < 8; ++e) rp[rs * 130 + g * 8 + e] = acc[e];
    __syncthreads();
    if (t < 128) {
        float p = 0.f;
        #pragma unroll
        for (int r2 = 0; r2 < 16; ++r2) p += rp[r2 * 130 + t];
        as_l[t] = p;
    }

    // ================= phase B: a_o = attn(br, xbo, xbo) (from P) =================
    if (t < 128) {
        int pib = (c + 1) * 512 - 64 + t;
        pib = min(pib, LSEQ - 1);
        int n2 = b * 64 + (pib >> 9);
        int row = (pib & 511) + 2;
        rb[t] = (n2 * PH + row) * DCH;
    }
    __syncthreads();
    #pragma unroll
    for (int r = 0; r < 8; ++r) {
        int row = rs * 8 + r;
        uint4 v = *(const uint4*)(P + rb[row] + g * 8);
        unsigned vv[4] = {v.x, v.y, v.z, v.w};
        float p = 0.f;
        #pragma unroll
        for (int e = 0; e < 4; ++e) {
            p += bf2f((unsigned short)(vv[e] & 0xffff)) * brv[2 * e];
            p += bf2f((unsigned short)(vv[e] >> 16))    * brv[2 * e + 1];
        }
        sp[row * 17 + g] = p;
    }
    __syncthreads();
    if (t < 128) {
        float p = 0.f;
        #pragma unroll
        for (int j = 0; j < 16; ++j) p += sp[t * 17 + j];
        s[t] = p * SCALE_F;
        red[t] = s[t];
    }
    __syncthreads();
    for (int off = 64; off > 0; off >>= 1) {
        if (t < off) red[t] = fmaxf(red[t], red[t + off]);
        __syncthreads();
    }
    float smaxB = red[0];
    __syncthreads();
    if (t < 128) {
        float e = expf(s[t] - smaxB);
        s[t] = e;
        red[t] = e;
    }
    __syncthreads();
    for (int off = 64; off > 0; off >>= 1) {
        if (t < off) red[t] += red[t + off];
        __syncthreads();
    }
    float invB = 1.f / red[0];
    __syncthreads();
    if (t < 128) s[t] *= invB;
    __syncthreads();
    float accB[8];
    #pragma unroll
    for (int e = 0; e < 8; ++e) accB[e] = 0.f;
    #pragma unroll
    for (int r = 0; r < 8; ++r) {
        int row = rs * 8 + r;
        float w = s[row];
        uint4 v = *(const uint4*)(P + rb[row] + g * 8);
        unsigned vv[4] = {v.x, v.y, v.z, v.w};
        #pragma unroll
        for (int e = 0; e < 4; ++e) {
            accB[2 * e]     += w * bf2f((unsigned short)(vv[e] & 0xffff));
            accB[2 * e + 1] += w * bf2f((unsigned short)(vv[e] >> 16));
        }
    }
    #pragma unroll
    for (int e = 0; e < 8; ++e) sp[rs * 130 + g * 8 + e] = accB[e];
    __syncthreads();
    if (t < 128) {
        float p = 0.f;
        #pragma unroll
        for (int r2 = 0; r2 < 16; ++r2) p += sp[r2 * 130 + t];
        ao_l[t] = p;
    }
    __syncthreads();

    // ================= phase C: out = concat(a_s,a_o,br) @ fusion_w + b =================
    float* fu = sp + 8320;
    if (t < 128) {
        fu[t] = as_l[t];
        fu[128 + t] = ao_l[t];
        fu[256 + t] = br[t];
    }
    __syncthreads();
    {
        int col = t & 127, h = t >> 7;
        float a2 = (h == 0) ? fusion_b[col] : 0.f;
        for (int j = h * 192; j < h * 192 + 192; ++j)
            a2 += fu[j] * fusion_w[j * DCH + col];
        sp[h * 128 + col] = a2;
    }
    __syncthreads();
    if (t < 128) {
        float v = sp[t] + sp[128 + t];
        out[n * DCH + t] = v;
        out[NB * 64 * DCH + n * DCH + t] = v;
    }
}

extern "C" void kernel_launch(void* const* d_in, const int* in_sizes, int n_in,
                              void* d_out, int out_size, void* d_ws, size_t ws_size,
                              hipStream_t stream) {
    const float* x        = (const float*)d_in[0];
    const float* w_lw     = (const float*)d_in[1];
    const float* b_lw     = (const float*)d_in[2];
    const float* conv_w   = (const float*)d_in[3];
    const float* conv_b   = (const float*)d_in[4];
    const float* fusion_w = (const float*)d_in[5];
    const float* fusion_b = (const float*)d_in[6];
    float* out = (float*)d_out;

    char* ws = (char*)d_ws;
    size_t off = 0;
    auto alloc = [&](size_t bytes) { char* p = ws + off; off += (bytes + 255) & ~(size_t)255; return p; };
    float* logits     = (float*)alloc(NB * LSEQ * 4);       // fallback only
    float* exg        = (float*)alloc(NB * LSEQ * 4);       // fallback only
    float* subM       = (float*)alloc(NSUB * 4);
    float* seedM      = (float*)alloc(NSUB * 4);
    float* S_w        = (float*)alloc(NSUB * 4);
    float* sS_w       = (float*)alloc(NSUB * 4);
    float* S_wx       = (float*)alloc((size_t)NSUB * DCH * 4);
    float* sS_wx      = (float*)alloc((size_t)NSUB * DCH * 4);
    float* block_repr = (float*)alloc(NBLK * DCH * 4);
    unsigned short* W3      = (unsigned short*)alloc(128 * 768 * 2);
    unsigned short* P       = (unsigned short*)alloc((size_t)NBLK * PH * DCH * 2);
    unsigned short* convout = (unsigned short*)alloc((size_t)NBLK * 512 * DCH * 2);

    k_init<<<NBLK, 256, 0, stream>>>(conv_w, W3, P);

    // Co-residency guard (capture-safe host queries, cached): only take the
    // cooperative path if the runtime guarantees all NCHUNK blocks resident.
    static int coop_ok = -1;
    if (coop_ok < 0) {
        int dev = 0, ncu = 0, maxb = 0;
        coop_ok = 0;
        if (hipGetDevice(&dev) == hipSuccess &&
            hipDeviceGetAttribute(&ncu, hipDeviceAttributeMultiprocessorCount, dev) == hipSuccess &&
            hipOccupancyMaxActiveBlocksPerMultiprocessor(&maxb, (const void*)k_front, 256, 0) == hipSuccess) {
            if ((long)maxb * ncu >= NCHUNK) coop_ok = 1;
        }
        (void)hipGetLastError();
    }

    bool coop_done = false;
    if (coop_ok == 1) {
        void* cargs[] = {(void*)&x, (void*)&w_lw, (void*)&b_lw, (void*)&subM, (void*)&seedM,
                         (void*)&S_w, (void*)&sS_w, (void*)&S_wx, (void*)&sS_wx, (void*)&P};
        hipError_t ce = hipLaunchCooperativeKernel((const void*)k_front, dim3(NCHUNK), dim3(256),
                                                   cargs, 0, stream);
        if (ce == hipSuccess) {
            coop_done = true;
        } else {
            (void)hipGetLastError();   // clear sticky error, fall back
            coop_ok = 0;               // don't retry on replays
        }
    }
    if (!coop_done) {
        k_logits2<<<NCHUNK, 256, 0, stream>>>(x, w_lw, b_lw, logits, subM);
        k_seed_max2<<<NB, 64, 0, stream>>>(subM, seedM);
        k_sums<<<NCHUNK, 256, 0, stream>>>(x, logits, seedM, exg, S_w, S_wx);
        k_seed_w<<<NB, 64, 0, stream>>>(S_w, sS_w);
        k_seed_sums2<<<NB * 8, 256, 0, stream>>>(S_wx, sS_wx);
        k_apply<<<NSUB / 2, 128, 0, stream>>>(x, exg, sS_w, sS_wx, P);
    }

    k_conv<<<NBLK * 4, 256, 0, stream>>>(P, W3, conv_b, convout);
    k_tail<<<NBLK, 256, 0, stream>>>(convout, P, fusion_w, fusion_b, block_repr, out);
}

// Round 8
// 349.295 us; speedup vs baseline: 1.1076x; 1.0016x over previous
//
#include <hip/hip_runtime.h>
#include <hip/hip_bf16.h>

// Problem constants (reference: D=128, BC=64, BS=512, K=6, OV=128, B=8)
#define NB 8            // batches
#define LSEQ 32768      // BC*BS positions per batch
#define DCH 128         // channels
#define NCHUNK 1024     // 256-row chunks
#define NSUB 4096       // 64-row sub-chunks
#define NBLK 512        // B*BC conv blocks
#define PH 520          // padded rows per block (2 front + 512 + pad, rounded)
#define SCALE_F 0.08838834764831845f

typedef __bf16 bf16x8 __attribute__((ext_vector_type(8)));
typedef float f32x4 __attribute__((ext_vector_type(4)));

__device__ __forceinline__ float bf2f(unsigned short u) {
    return __uint_as_float(((unsigned)u) << 16);
}
__device__ __forceinline__ unsigned short f2bf(float f) {
    unsigned u = __float_as_uint(f);
    u += 0x7fffu + ((u >> 16) & 1u);   // round-to-nearest-even
    return (unsigned short)(u >> 16);
}

// async global->LDS DMA, 16 B per lane; LDS dest = wave-uniform base + lane*16
__device__ __forceinline__ void async_copy16(const void* gsrc, void* ldst) {
    __builtin_amdgcn_global_load_lds(
        (const __attribute__((address_space(1))) unsigned int*)gsrc,
        (__attribute__((address_space(3))) unsigned int*)ldst, 16, 0, 0);
}

// NOTE (R6 post-mortem): cooperative k_front REFUTED — grid.sync() on 1024 blocks
// cost ~400 µs of spin (VALUBusy 2.6%); coop also fails under graph capture so the
// timed/profiled paths diverged. Plain kernel chain is the design.

// ---------------- Stage 1: logits = silu(x @ w_lw + b); per-64-row-sub max ----------------
// Column-parallel dot (LDS partials), no per-row shuffle trees.
// NOTE (R5/R6 post-mortem): reference weights are w_i = exp(l_i - cummax_i) —
// frozen at insertion, never rescaled. The cummax does NOT cancel. Keep it.
__global__ __launch_bounds__(256) void k_logits2(const float* __restrict__ x,
                                                 const float* __restrict__ w_lw,
                                                 const float* __restrict__ b_lw,
                                                 float* __restrict__ logits,
                                                 float* __restrict__ subM) {
    int chunk = blockIdx.x, t = threadIdx.x;
    int g = t & 15, rs = t >> 4;
    __shared__ float sp[256 * 17];
    __shared__ float red[256];
    float wv[8];
    #pragma unroll
    for (int e = 0; e < 8; ++e) wv[e] = w_lw[g * 8 + e];
    float bb = b_lw[0];
    size_t base = (size_t)chunk * 256 * DCH;
    for (int i = 0; i < 16; ++i) {
        int row = rs * 16 + i;
        float4 a  = *(const float4*)(x + base + (size_t)row * DCH + g * 8);
        float4 b4 = *(const float4*)(x + base + (size_t)row * DCH + g * 8 + 4);
        sp[row * 17 + g] = a.x * wv[0] + a.y * wv[1] + a.z * wv[2] + a.w * wv[3] +
                           b4.x * wv[4] + b4.y * wv[5] + b4.z * wv[6] + b4.w * wv[7];
    }
    __syncthreads();
    float s = bb;
    #pragma unroll
    for (int j = 0; j < 16; ++j) s += sp[t * 17 + j];
    float l = s / (1.f + expf(-s));          // silu
    logits[(size_t)chunk * 256 + t] = l;
    red[t] = l;
    __syncthreads();
    for (int off = 32; off >= 1; off >>= 1) {
        if ((t & 63) < off) red[t] = fmaxf(red[t], red[t + off]);
        __syncthreads();
    }
    if ((t & 63) == 0) subM[chunk * 4 + (t >> 6)] = red[t];
}

// ---------------- Stage 2: exclusive prefix-MAX over 512 subs per batch ----------------
__global__ __launch_bounds__(64) void k_seed_max2(const float* __restrict__ subM,
                                                  float* __restrict__ seedM) {
    int b = blockIdx.x, lane = threadIdx.x;
    const float* src = subM + b * 512;
    float* dst = seedM + b * 512;
    float v[8];
    float m = -INFINITY;
    #pragma unroll
    for (int j = 0; j < 8; ++j) { v[j] = src[lane * 8 + j]; m = fmaxf(m, v[j]); }
    float incl = m;
    #pragma unroll
    for (int off = 1; off < 64; off <<= 1) {
        float o = __shfl_up(incl, off, 64);
        if (lane >= off) incl = fmaxf(incl, o);
    }
    float ex = __shfl_up(incl, 1, 64);
    if (lane == 0) ex = -INFINITY;
    float run = ex;
    #pragma unroll
    for (int j = 0; j < 8; ++j) { dst[lane * 8 + j] = run; run = fmaxf(run, v[j]); }
}

// ---------------- Stage 3: w_i = exp(l_i - max(seedM, cummax_loc)); sub sums ----------------
// Serial if(t<4) 64-deep chain replaced by a 64-lane shfl_up inclusive prefix-max
// per wave — BIT-EXACT (fmax exact+associative, identical expf inputs), 252 idle
// lanes -> 0.
__global__ __launch_bounds__(256) void k_sums(const float* __restrict__ x,
                                              const float* __restrict__ logits,
                                              const float* __restrict__ seedM,
                                              float* __restrict__ exg,
                                              float* __restrict__ S_w,
                                              float* __restrict__ S_wx) {
    int chunk = blockIdx.x, t = threadIdx.x;
    int g = t & 15, rs = t >> 4;
    int w = t >> 6, lane = t & 63;
    __shared__ float wbuf[256];
    __shared__ float red[256];
    __shared__ float rp[16 * 130];
    float l = logits[(size_t)chunk * 256 + t];
    float M = seedM[chunk * 4 + w];
    float incl = l;                          // inclusive prefix-max within sub
    #pragma unroll
    for (int off = 1; off < 64; off <<= 1) {
        float o = __shfl_up(incl, off, 64);
        if (lane >= off) incl = fmaxf(incl, o);
    }
    float w_t = expf(l - fmaxf(M, incl));
    wbuf[t] = w_t;
    exg[(size_t)chunk * 256 + t] = w_t;
    red[t] = w_t;
    __syncthreads();
    for (int off = 32; off >= 1; off >>= 1) {
        if ((t & 63) < off) red[t] += red[t + off];
        __syncthreads();
    }
    if ((t & 63) == 0) S_w[chunk * 4 + (t >> 6)] = red[t];
    // column-parallel S_wx: thread (g,rs) covers rows rs*16..+15 (all in sub rs>>2)
    float acc[8];
    #pragma unroll
    for (int e = 0; e < 8; ++e) acc[e] = 0.f;
    size_t base = (size_t)chunk * 256 * DCH;
    for (int i = 0; i < 16; ++i) {
        int row = rs * 16 + i;
        float ww = wbuf[row];
        float4 a  = *(const float4*)(x + base + (size_t)row * DCH + g * 8);
        float4 b4 = *(const float4*)(x + base + (size_t)row * DCH + g * 8 + 4);
        acc[0] += ww * a.x;  acc[1] += ww * a.y;  acc[2] += ww * a.z;  acc[3] += ww * a.w;
        acc[4] += ww * b4.x; acc[5] += ww * b4.y; acc[6] += ww * b4.z; acc[7] += ww * b4.w;
    }
    #pragma unroll
    for (int e = 0; e < 8; ++e) rp[rs * 130 + g * 8 + e] = acc[e];
    __syncthreads();
    #pragma unroll
    for (int k = 0; k < 2; ++k) {
        int idx = k * 256 + t;                 // 4 subs x 128 ch
        int sub = idx >> 7, c = idx & 127;
        float sm = rp[(sub * 4 + 0) * 130 + c] + rp[(sub * 4 + 1) * 130 + c] +
                   rp[(sub * 4 + 2) * 130 + c] + rp[(sub * 4 + 3) * 130 + c];
        S_wx[((size_t)chunk * 4 + sub) * DCH + c] = sm;
    }
}

// ---------------- Stage 4 merged: both seed scans in one launch ----------------
// blocks 0..7: exclusive prefix-SUM of S_w (wave scan, 64 lanes used)
// blocks 8..71: exclusive prefix-SUM of S_wx per channel (batch, 16-ch group)
__global__ __launch_bounds__(256) void k_seed_both(const float* __restrict__ S_w,
                                                   float* __restrict__ sS_w,
                                                   const float* __restrict__ S_wx,
                                                   float* __restrict__ sS_wx) {
    int blk = blockIdx.x, t = threadIdx.x;
    if (blk < 8) {
        if (t < 64) {
            const float* src = S_w + blk * 512;
            float* dst = sS_w + blk * 512;
            float v[8];
            float tot = 0.f;
            #pragma unroll
            for (int j = 0; j < 8; ++j) { v[j] = src[t * 8 + j]; tot += v[j]; }
            float incl = tot;
            #pragma unroll
            for (int off = 1; off < 64; off <<= 1) {
                float o = __shfl_up(incl, off, 64);
                if (t >= off) incl += o;
            }
            float ex = __shfl_up(incl, 1, 64);
            if (t == 0) ex = 0.f;
            float run = ex;
            #pragma unroll
            for (int j = 0; j < 8; ++j) { dst[t * 8 + j] = run; run += v[j]; }
        }
        return;
    }
    int b = (blk - 8) >> 3, cgx = (blk - 8) & 7;
    int cl = t & 15, seg = t >> 4;
    int c = cgx * 16 + cl;
    __shared__ float tots[16][17];
    const float* src = S_wx + (size_t)b * 512 * DCH + c;
    float* dst = sS_wx + (size_t)b * 512 * DCH + c;
    int s0 = seg * 32;
    float tot = 0.f;
    for (int j = 0; j < 32; ++j) tot += src[(size_t)(s0 + j) * DCH];
    tots[seg][cl] = tot;
    __syncthreads();
    if (t < 16) {
        float run = 0.f;
        for (int s = 0; s < 16; ++s) { float tmp = tots[s][t]; tots[s][t] = run; run += tmp; }
    }
    __syncthreads();
    float run = tots[seg][cl];
    for (int j = 0; j < 32; ++j) {
        float val = src[(size_t)(s0 + j) * DCH];
        dst[(size_t)(s0 + j) * DCH] = run;
        run += val;
    }
}

// ---------------- merged init: zero halo rows of P + weight repack W3 ----------------
// W3 flat index f = (((kt*2+ks)*4 + kchunk)*128 + o)*8 + e
//   maps to conv_w[o][ i ][ kn ],  i = (kt&1)*64 + (ks*4+kchunk)*8 + e,  kn = kt>>1.
__global__ __launch_bounds__(256) void k_init(const float* __restrict__ conv_w,
                                              unsigned short* __restrict__ W3,
                                              unsigned short* __restrict__ P) {
    int n = blockIdx.x, t = threadIdx.x;
    for (int i = t; i < 1024; i += 256) {
        int rr = i >> 7;                       // 0..7
        int row = (rr < 2) ? rr : 512 + rr;    // rows 0,1,514..519
        P[(n * PH + row) * DCH + (i & 127)] = 0;
    }
    int idx = n * 256 + t;                     // blocks 0..383 cover 98304 elems
    if (idx < 98304) {
        int e  = idx & 7;
        int o  = (idx >> 3) & 127;
        int kc = (idx >> 10) & 3;
        int kt2 = idx >> 12;                   // 0..23 = kt*2+ks
        int kt = kt2 >> 1, ks = kt2 & 1;
        int i  = (kt & 1) * 64 + (ks * 4 + kc) * 8 + e;
        int kn = kt >> 1;
        W3[idx] = f2bf(conv_w[(o * 128 + i) * 6 + kn]);
    }
}

// ---------------- Stage 5: apply scan -> prefix_x, write bf16 padded P ----------------
// 256-thread blocks (4 subs/block, 1024 blocks) + hardware rcp (v_rcp_f32,
// ~1e-7 rel err << bf16 quantum 4e-3) replacing the precise-div chain.
__global__ __launch_bounds__(256) void k_apply(const float* __restrict__ x,
                                               const float* __restrict__ exg,
                                               const float* __restrict__ sS_w,
                                               const float* __restrict__ sS_wx,
                                               unsigned short* __restrict__ P) {
    int t = threadIdx.x, w = t >> 6, lane = t & 63;
    int s = blockIdx.x * 4 + w;                // sub-chunk id
    int b = s >> 9, sb = s & 511;
    __shared__ float e2[256];
    e2[t] = exg[(size_t)blockIdx.x * 256 + t]; // all 4 waves' w values
    float2 axx = *(const float2*)(sS_wx + (size_t)s * DCH + 2 * lane);
    float aex = sS_w[s];
    __syncthreads();
    const float* es = e2 + w * 64;
    int pib0 = sb * 64;
    int n = b * 64 + (pib0 >> 9);
    int row0 = (pib0 & 511) + 2;
    const float* xp = x + ((size_t)b * LSEQ + pib0) * DCH + 2 * lane;
    unsigned short* pp = P + ((size_t)n * PH + row0) * DCH + 2 * lane;
    for (int j = 0; j < 64; ++j) {
        float e = es[j];
        aex += e;
        float2 xv = *(const float2*)xp;
        axx.x += e * xv.x;
        axx.y += e * xv.y;
        float inv = __builtin_amdgcn_rcpf(aex);
        unsigned pk = ((unsigned)f2bf(axx.y * inv + xv.y) << 16) | f2bf(axx.x * inv + xv.x);
        *(unsigned*)pp = pk;
        xp += DCH;
        pp += DCH;
    }
}

// ---------------- Stage 6: conv as bf16 MFMA GEMM (128x128 tile, K=768) ----------------
// Panel staged ONCE (144 rows x 128 ch, 36 KB, one barrier); 12 K-steps barrier-free
// reading kn-shifted windows. Swizzle: physical chunk = (c&8) | ((c&7) ^ (gr&7)) at
// the DMA *source* (LDS dest linear, rule 21), inverted on ds_read. B register-direct
// from L2-resident W3 (double-buffered).
__global__ __launch_bounds__(256) void k_conv(const unsigned short* __restrict__ P,
                                              const unsigned short* __restrict__ W3,
                                              const float* __restrict__ conv_b,
                                              unsigned short* __restrict__ convout) {
    int n = blockIdx.x >> 2;
    int h0 = (blockIdx.x & 3) * 128;
    __shared__ __align__(16) char panel[144 * 256];   // 36864 B; epilogue reuses first 34816 B
    int t = threadIdx.x;
    int wave = t >> 6, lane = t & 63;
    f32x4 acc[4][4] = {};
    const unsigned short* Pn = P + (size_t)n * PH * DCH;
    int wm = (wave >> 1) * 64, wn = (wave & 1) * 64;
    int kchunk = lane >> 4;                   // 0..3 (MFMA k-slice group)
    int bcol = wn + (lane & 15);              // B out-channel base (+ni*16)

    bf16x8 breg[2][8];

    auto loadB = [&](int kt, bf16x8* dstB) {
        #pragma unroll
        for (int ks = 0; ks < 2; ++ks)
            #pragma unroll
            for (int ni = 0; ni < 4; ++ni)
                dstB[ks * 4 + ni] = *(const bf16x8*)(
                    W3 + (size_t)((kt * 2 + ks) * 4 + kchunk) * 1024 + (bcol + ni * 16) * 8);
    };

    // ---- stage the full panel: 9 rounds x (4 waves x 64 lanes x 16 B) = 144 rows ----
    {
        int c = lane & 15;                    // physical 16B-chunk within row
        #pragma unroll
        for (int j = 0; j < 9; ++j) {
            int r = j * 16 + wave * 4 + (lane >> 4);    // LDS row 0..143
            int gr = h0 + r;                             // global padded row
            int grc = min(gr, PH - 1);                   // clamp: rows >519 unread
            int srcc = (c & 8) | ((c & 7) ^ (gr & 7));   // source-side swizzle
            async_copy16(Pn + (size_t)grc * DCH + srcc * 8,
                         panel + j * 4096 + wave * 1024 + lane * 16);
        }
    }
    loadB(0, breg[0]);
    __syncthreads();                           // drains vmcnt(0): panel + breg[0] ready

    // ---- 12 K-steps, NO barriers: pure ds_read + MFMA on the resident panel ----
    #pragma unroll
    for (int kt = 0; kt < 12; ++kt) {
        if (kt < 11) loadB(kt + 1, breg[(kt + 1) & 1]);   // prefetch next B from L2
        int kn = kt >> 1;
        int cb = (kt & 1) * 8;                 // chunk-half: channels 0..63 / 64..127
        #pragma unroll
        for (int ks = 0; ks < 2; ++ks) {
            bf16x8 af[4];
            #pragma unroll
            for (int mi = 0; mi < 4; ++mi) {
                int row = wm + mi * 16 + (lane & 15) + kn;          // panel row
                int phys = cb + ((ks * 4 + kchunk) ^ ((h0 + row) & 7));
                af[mi] = *(const bf16x8*)(panel + row * 256 + phys * 16);
            }
            #pragma unroll
            for (int mi = 0; mi < 4; ++mi)
                #pragma unroll
                for (int ni = 0; ni < 4; ++ni)
                    acc[mi][ni] = __builtin_amdgcn_mfma_f32_16x16x32_bf16(af[mi],
                                                                          breg[kt & 1][ks * 4 + ni],
                                                                          acc[mi][ni], 0, 0, 0);
        }
    }
    __syncthreads();   // all panel reads complete before C-stage overwrite
    // C/D layout: col=lane&15, row=(lane>>4)*4+reg  [m89-verified]
    unsigned short* clds = (unsigned short*)panel;
    #pragma unroll
    for (int mi = 0; mi < 4; ++mi)
        #pragma unroll
        for (int ni = 0; ni < 4; ++ni) {
            int col = wn + ni * 16 + (lane & 15);
            float bias = conv_b[col];
            #pragma unroll
            for (int r = 0; r < 4; ++r) {
                int row = wm + mi * 16 + (lane >> 4) * 4 + r;
                clds[row * 136 + col] = f2bf(acc[mi][ni][r] + bias);
            }
        }
    __syncthreads();
    // coalesced store: 2048 granules of 16 B
    size_t base = (size_t)(n * 512 + h0) * DCH;
    #pragma unroll
    for (int it = 0; it < 8; ++it) {
        int idx = it * 256 + t;
        int row = idx >> 4, g = idx & 15;
        uint4 v = *(const uint4*)(clds + row * 136 + g * 8);
        *(uint4*)(convout + base + (size_t)row * DCH + g * 8) = v;
    }
}

// ---------------- Stage 7-9 fused tail: block_repr + a_s + a_o + fusion, one block per n ----
__global__ __launch_bounds__(256) void k_tail(const unsigned short* __restrict__ conv,
                                              const unsigned short* __restrict__ P,
                                              const float* __restrict__ fusion_w,
                                              const float* __restrict__ fusion_b,
                                              float* __restrict__ block_repr,
                                              float* __restrict__ out) {
    int n = blockIdx.x, t = threadIdx.x;
    int g = t & 15, rs = t >> 4;
    int b = n >> 6, c = n & 63;
    __shared__ __align__(16) float sp[512 * 17];   // partials / rp[16][130] / red / fu / comb
    __shared__ float s[512];
    __shared__ float br[128];
    __shared__ float as_l[128];
    __shared__ float ao_l[128];
    __shared__ float red[128];
    __shared__ int rb[128];
    float* rp = sp;                                 // [16][130] view
    const unsigned short* base = conv + (size_t)n * 512 * DCH;

    // ================= phase A: block_repr + a_s (from convout) =================
    float m[8];
    #pragma unroll
    for (int e = 0; e < 8; ++e) m[e] = -INFINITY;
    for (int i = 0; i < 32; ++i) {
        int row = i * 16 + rs;
        uint4 v = *(const uint4*)(base + row * DCH + g * 8);
        unsigned vv[4] = {v.x, v.y, v.z, v.w};
        #pragma unroll
        for (int e = 0; e < 4; ++e) {
            m[2 * e]     = fmaxf(m[2 * e],     bf2f((unsigned short)(vv[e] & 0xffff)));
            m[2 * e + 1] = fmaxf(m[2 * e + 1], bf2f((unsigned short)(vv[e] >> 16)));
        }
    }
    #pragma unroll
    for (int e = 0; e < 8; ++e) rp[rs * 130 + g * 8 + e] = m[e];
    __syncthreads();
    if (t < 128) {
        float bm = rp[t];
        #pragma unroll
        for (int r2 = 1; r2 < 16; ++r2) bm = fmaxf(bm, rp[r2 * 130 + t]);
        br[t] = bm;
        block_repr[n * DCH + t] = bm;
    }
    __syncthreads();

    float brv[8];
    #pragma unroll
    for (int e = 0; e < 8; ++e) brv[e] = br[g * 8 + e];
    for (int i = 0; i < 32; ++i) {
        int row = i * 16 + rs;
        uint4 v = *(const uint4*)(base + row * DCH + g * 8);
        unsigned vv[4] = {v.x, v.y, v.z, v.w};
        float p = 0.f;
        #pragma unroll
        for (int e = 0; e < 4; ++e) {
            p += bf2f((unsigned short)(vv[e] & 0xffff)) * brv[2 * e];
            p += bf2f((unsigned short)(vv[e] >> 16))    * brv[2 * e + 1];
        }
        sp[row * 17 + g] = p;
    }
    __syncthreads();
    #pragma unroll
    for (int rr = 0; rr < 2; ++rr) {
        int row = t * 2 + rr;
        float p = 0.f;
        #pragma unroll
        for (int j = 0; j < 16; ++j) p += sp[row * 17 + j];
        s[row] = p * SCALE_F;
    }
    __syncthreads();

    float* redA = sp;
    float mm = fmaxf(s[t], s[t + 256]);
    __syncthreads();
    redA[t] = mm;
    __syncthreads();
    for (int off = 128; off > 0; off >>= 1) {
        if (t < off) redA[t] = fmaxf(redA[t], redA[t + off]);
        __syncthreads();
    }
    float smax = redA[0];
    __syncthreads();
    float e0 = expf(s[t] - smax), e1 = expf(s[t + 256] - smax);
    redA[t] = e0 + e1;
    __syncthreads();
    for (int off = 128; off > 0; off >>= 1) {
        if (t < off) redA[t] += redA[t + off];
        __syncthreads();
    }
    float inv = 1.f / redA[0];
    __syncthreads();
    s[t] = e0 * inv;
    s[t + 256] = e1 * inv;
    __syncthreads();

    float acc[8];
    #pragma unroll
    for (int e = 0; e < 8; ++e) acc[e] = 0.f;
    for (int i = 0; i < 32; ++i) {
        int row = i * 16 + rs;
        float w = s[row];
        uint4 v = *(const uint4*)(base + row * DCH + g * 8);
        unsigned vv[4] = {v.x, v.y, v.z, v.w};
        #pragma unroll
        for (int e = 0; e < 4; ++e) {
            acc[2 * e]     += w * bf2f((unsigned short)(vv[e] & 0xffff));
            acc[2 * e + 1] += w * bf2f((unsigned short)(vv[e] >> 16));
        }
    }
    #pragma unroll
    for (int e = 0; e < 8; ++e) rp[rs * 130 + g * 8 + e] = acc[e];
    __syncthreads();
    if (t < 128) {
        float p = 0.f;
        #pragma unroll
        for (int r2 = 0; r2 < 16; ++r2) p += rp[r2 * 130 + t];
        as_l[t] = p;
    }

    // ================= phase B: a_o = attn(br, xbo, xbo) (from P) =================
    if (t < 128) {
        int pib = (c + 1) * 512 - 64 + t;
        pib = min(pib, LSEQ - 1);
        int n2 = b * 64 + (pib >> 9);
        int row = (pib & 511) + 2;
        rb[t] = (n2 * PH + row) * DCH;
    }
    __syncthreads();
    #pragma unroll
    for (int r = 0; r < 8; ++r) {
        int row = rs * 8 + r;
        uint4 v = *(const uint4*)(P + rb[row] + g * 8);
        unsigned vv[4] = {v.x, v.y, v.z, v.w};
        float p = 0.f;
        #pragma unroll
        for (int e = 0; e < 4; ++e) {
            p += bf2f((unsigned short)(vv[e] & 0xffff)) * brv[2 * e];
            p += bf2f((unsigned short)(vv[e] >> 16))    * brv[2 * e + 1];
        }
        sp[row * 17 + g] = p;
    }
    __syncthreads();
    if (t < 128) {
        float p = 0.f;
        #pragma unroll
        for (int j = 0; j < 16; ++j) p += sp[t * 17 + j];
        s[t] = p * SCALE_F;
        red[t] = s[t];
    }
    __syncthreads();
    for (int off = 64; off > 0; off >>= 1) {
        if (t < off) red[t] = fmaxf(red[t], red[t + off]);
        __syncthreads();
    }
    float smaxB = red[0];
    __syncthreads();
    if (t < 128) {
        float e = expf(s[t] - smaxB);
        s[t] = e;
        red[t] = e;
    }
    __syncthreads();
    for (int off = 64; off > 0; off >>= 1) {
        if (t < off) red[t] += red[t + off];
        __syncthreads();
    }
    float invB = 1.f / red[0];
    __syncthreads();
    if (t < 128) s[t] *= invB;
    __syncthreads();
    float accB[8];
    #pragma unroll
    for (int e = 0; e < 8; ++e) accB[e] = 0.f;
    #pragma unroll
    for (int r = 0; r < 8; ++r) {
        int row = rs * 8 + r;
        float w = s[row];
        uint4 v = *(const uint4*)(P + rb[row] + g * 8);
        unsigned vv[4] = {v.x, v.y, v.z, v.w};
        #pragma unroll
        for (int e = 0; e < 4; ++e) {
            accB[2 * e]     += w * bf2f((unsigned short)(vv[e] & 0xffff));
            accB[2 * e + 1] += w * bf2f((unsigned short)(vv[e] >> 16));
        }
    }
    #pragma unroll
    for (int e = 0; e < 8; ++e) sp[rs * 130 + g * 8 + e] = accB[e];
    __syncthreads();
    if (t < 128) {
        float p = 0.f;
        #pragma unroll
        for (int r2 = 0; r2 < 16; ++r2) p += sp[r2 * 130 + t];
        ao_l[t] = p;
    }
    __syncthreads();

    // ================= phase C: out = concat(a_s,a_o,br) @ fusion_w + b =================
    float* fu = sp + 8320;
    if (t < 128) {
        fu[t] = as_l[t];
        fu[128 + t] = ao_l[t];
        fu[256 + t] = br[t];
    }
    __syncthreads();
    {
        int col = t & 127, h = t >> 7;
        float a2 = (h == 0) ? fusion_b[col] : 0.f;
        for (int j = h * 192; j < h * 192 + 192; ++j)
            a2 += fu[j] * fusion_w[j * DCH + col];
        sp[h * 128 + col] = a2;
    }
    __syncthreads();
    if (t < 128) {
        float v = sp[t] + sp[128 + t];
        out[n * DCH + t] = v;
        out[NB * 64 * DCH + n * DCH + t] = v;
    }
}

extern "C" void kernel_launch(void* const* d_in, const int* in_sizes, int n_in,
                              void* d_out, int out_size, void* d_ws, size_t ws_size,
                              hipStream_t stream) {
    const float* x        = (const float*)d_in[0];
    const float* w_lw     = (const float*)d_in[1];
    const float* b_lw     = (const float*)d_in[2];
    const float* conv_w   = (const float*)d_in[3];
    const float* conv_b   = (const float*)d_in[4];
    const float* fusion_w = (const float*)d_in[5];
    const float* fusion_b = (const float*)d_in[6];
    float* out = (float*)d_out;

    char* ws = (char*)d_ws;
    size_t off = 0;
    auto alloc = [&](size_t bytes) { char* p = ws + off; off += (bytes + 255) & ~(size_t)255; return p; };
    float* logits     = (float*)alloc(NB * LSEQ * 4);
    float* exg        = (float*)alloc(NB * LSEQ * 4);
    float* subM       = (float*)alloc(NSUB * 4);
    float* seedM      = (float*)alloc(NSUB * 4);
    float* S_w        = (float*)alloc(NSUB * 4);
    float* sS_w       = (float*)alloc(NSUB * 4);
    float* S_wx       = (float*)alloc((size_t)NSUB * DCH * 4);
    float* sS_wx      = (float*)alloc((size_t)NSUB * DCH * 4);
    float* block_repr = (float*)alloc(NBLK * DCH * 4);
    unsigned short* W3      = (unsigned short*)alloc(128 * 768 * 2);
    unsigned short* P       = (unsigned short*)alloc((size_t)NBLK * PH * DCH * 2);
    unsigned short* convout = (unsigned short*)alloc((size_t)NBLK * 512 * DCH * 2);

    k_init<<<NBLK, 256, 0, stream>>>(conv_w, W3, P);
    k_logits2<<<NCHUNK, 256, 0, stream>>>(x, w_lw, b_lw, logits, subM);
    k_seed_max2<<<NB, 64, 0, stream>>>(subM, seedM);
    k_sums<<<NCHUNK, 256, 0, stream>>>(x, logits, seedM, exg, S_w, S_wx);
    k_seed_both<<<72, 256, 0, stream>>>(S_w, sS_w, S_wx, sS_wx);
    k_apply<<<NSUB / 4, 256, 0, stream>>>(x, exg, sS_w, sS_wx, P);
    k_conv<<<NBLK * 4, 256, 0, stream>>>(P, W3, conv_b, convout);
    k_tail<<<NBLK, 256, 0, stream>>>(convout, P, fusion_w, fusion_b, block_repr, out);
}

// Round 9
// 342.825 us; speedup vs baseline: 1.1285x; 1.0189x over previous
//
#include <hip/hip_runtime.h>
#include <hip/hip_bf16.h>

// Problem constants (reference: D=128, BC=64, BS=512, K=6, OV=128, B=8)
#define NB 8            // batches
#define LSEQ 32768      // BC*BS positions per batch
#define DCH 128         // channels
#define NCHUNK 1024     // 256-row chunks
#define NSUB 4096       // 64-row sub-chunks
#define NBLK 512        // B*BC conv blocks
#define PH 520          // padded rows per block (2 front + 512 + pad, rounded)
#define SCALE_F 0.08838834764831845f

typedef __bf16 bf16x8 __attribute__((ext_vector_type(8)));
typedef float f32x4 __attribute__((ext_vector_type(4)));

__device__ __forceinline__ float bf2f(unsigned short u) {
    return __uint_as_float(((unsigned)u) << 16);
}
__device__ __forceinline__ unsigned short f2bf(float f) {
    unsigned u = __float_as_uint(f);
    u += 0x7fffu + ((u >> 16) & 1u);   // round-to-nearest-even
    return (unsigned short)(u >> 16);
}

// async global->LDS DMA, 16 B per lane; LDS dest = wave-uniform base + lane*16
__device__ __forceinline__ void async_copy16(const void* gsrc, void* ldst) {
    __builtin_amdgcn_global_load_lds(
        (const __attribute__((address_space(1))) unsigned int*)gsrc,
        (__attribute__((address_space(3))) unsigned int*)ldst, 16, 0, 0);
}

// NOTE (R6 post-mortem): cooperative k_front REFUTED — grid.sync() on 1024 blocks
// cost ~400 µs of spin (VALUBusy 2.6%); coop also fails under graph capture so the
// timed/profiled paths diverged. Plain kernel chain is the design.
// NOTE (R8 post-mortem): front-half VALU micro-opts (wave-parallel prefix-max, rcp,
// merged seed scans) were NEUTRAL — front kernels are memory/latency-bound.

// ---------------- Stage 1: logits = silu(x @ w_lw + b); per-64-row-sub max ----------------
__global__ __launch_bounds__(256) void k_logits2(const float* __restrict__ x,
                                                 const float* __restrict__ w_lw,
                                                 const float* __restrict__ b_lw,
                                                 float* __restrict__ logits,
                                                 float* __restrict__ subM) {
    int chunk = blockIdx.x, t = threadIdx.x;
    int g = t & 15, rs = t >> 4;
    __shared__ float sp[256 * 17];
    __shared__ float red[256];
    float wv[8];
    #pragma unroll
    for (int e = 0; e < 8; ++e) wv[e] = w_lw[g * 8 + e];
    float bb = b_lw[0];
    size_t base = (size_t)chunk * 256 * DCH;
    for (int i = 0; i < 16; ++i) {
        int row = rs * 16 + i;
        float4 a  = *(const float4*)(x + base + (size_t)row * DCH + g * 8);
        float4 b4 = *(const float4*)(x + base + (size_t)row * DCH + g * 8 + 4);
        sp[row * 17 + g] = a.x * wv[0] + a.y * wv[1] + a.z * wv[2] + a.w * wv[3] +
                           b4.x * wv[4] + b4.y * wv[5] + b4.z * wv[6] + b4.w * wv[7];
    }
    __syncthreads();
    float s = bb;
    #pragma unroll
    for (int j = 0; j < 16; ++j) s += sp[t * 17 + j];
    float l = s / (1.f + expf(-s));          // silu
    logits[(size_t)chunk * 256 + t] = l;
    red[t] = l;
    __syncthreads();
    for (int off = 32; off >= 1; off >>= 1) {
        if ((t & 63) < off) red[t] = fmaxf(red[t], red[t + off]);
        __syncthreads();
    }
    if ((t & 63) == 0) subM[chunk * 4 + (t >> 6)] = red[t];
}

// ---------------- Stage 2: exclusive prefix-MAX over 512 subs per batch ----------------
__global__ __launch_bounds__(64) void k_seed_max2(const float* __restrict__ subM,
                                                  float* __restrict__ seedM) {
    int b = blockIdx.x, lane = threadIdx.x;
    const float* src = subM + b * 512;
    float* dst = seedM + b * 512;
    float v[8];
    float m = -INFINITY;
    #pragma unroll
    for (int j = 0; j < 8; ++j) { v[j] = src[lane * 8 + j]; m = fmaxf(m, v[j]); }
    float incl = m;
    #pragma unroll
    for (int off = 1; off < 64; off <<= 1) {
        float o = __shfl_up(incl, off, 64);
        if (lane >= off) incl = fmaxf(incl, o);
    }
    float ex = __shfl_up(incl, 1, 64);
    if (lane == 0) ex = -INFINITY;
    float run = ex;
    #pragma unroll
    for (int j = 0; j < 8; ++j) { dst[lane * 8 + j] = run; run = fmaxf(run, v[j]); }
}

// ---------------- Stage 3: w_i = exp(l_i - max(seedM, cummax_loc)); sub sums ----------------
__global__ __launch_bounds__(256) void k_sums(const float* __restrict__ x,
                                              const float* __restrict__ logits,
                                              const float* __restrict__ seedM,
                                              float* __restrict__ exg,
                                              float* __restrict__ S_w,
                                              float* __restrict__ S_wx) {
    int chunk = blockIdx.x, t = threadIdx.x;
    int g = t & 15, rs = t >> 4;
    int w = t >> 6, lane = t & 63;
    __shared__ float wbuf[256];
    __shared__ float red[256];
    __shared__ float rp[16 * 130];
    float l = logits[(size_t)chunk * 256 + t];
    float M = seedM[chunk * 4 + w];
    float incl = l;                          // inclusive prefix-max within sub
    #pragma unroll
    for (int off = 1; off < 64; off <<= 1) {
        float o = __shfl_up(incl, off, 64);
        if (lane >= off) incl = fmaxf(incl, o);
    }
    float w_t = expf(l - fmaxf(M, incl));
    wbuf[t] = w_t;
    exg[(size_t)chunk * 256 + t] = w_t;
    red[t] = w_t;
    __syncthreads();
    for (int off = 32; off >= 1; off >>= 1) {
        if ((t & 63) < off) red[t] += red[t + off];
        __syncthreads();
    }
    if ((t & 63) == 0) S_w[chunk * 4 + (t >> 6)] = red[t];
    // column-parallel S_wx: thread (g,rs) covers rows rs*16..+15 (all in sub rs>>2)
    float acc[8];
    #pragma unroll
    for (int e = 0; e < 8; ++e) acc[e] = 0.f;
    size_t base = (size_t)chunk * 256 * DCH;
    for (int i = 0; i < 16; ++i) {
        int row = rs * 16 + i;
        float ww = wbuf[row];
        float4 a  = *(const float4*)(x + base + (size_t)row * DCH + g * 8);
        float4 b4 = *(const float4*)(x + base + (size_t)row * DCH + g * 8 + 4);
        acc[0] += ww * a.x;  acc[1] += ww * a.y;  acc[2] += ww * a.z;  acc[3] += ww * a.w;
        acc[4] += ww * b4.x; acc[5] += ww * b4.y; acc[6] += ww * b4.z; acc[7] += ww * b4.w;
    }
    #pragma unroll
    for (int e = 0; e < 8; ++e) rp[rs * 130 + g * 8 + e] = acc[e];
    __syncthreads();
    #pragma unroll
    for (int k = 0; k < 2; ++k) {
        int idx = k * 256 + t;                 // 4 subs x 128 ch
        int sub = idx >> 7, c = idx & 127;
        float sm = rp[(sub * 4 + 0) * 130 + c] + rp[(sub * 4 + 1) * 130 + c] +
                   rp[(sub * 4 + 2) * 130 + c] + rp[(sub * 4 + 3) * 130 + c];
        S_wx[((size_t)chunk * 4 + sub) * DCH + c] = sm;
    }
}

// ---------------- Stage 4 merged: both seed scans in one launch ----------------
__global__ __launch_bounds__(256) void k_seed_both(const float* __restrict__ S_w,
                                                   float* __restrict__ sS_w,
                                                   const float* __restrict__ S_wx,
                                                   float* __restrict__ sS_wx) {
    int blk = blockIdx.x, t = threadIdx.x;
    if (blk < 8) {
        if (t < 64) {
            const float* src = S_w + blk * 512;
            float* dst = sS_w + blk * 512;
            float v[8];
            float tot = 0.f;
            #pragma unroll
            for (int j = 0; j < 8; ++j) { v[j] = src[t * 8 + j]; tot += v[j]; }
            float incl = tot;
            #pragma unroll
            for (int off = 1; off < 64; off <<= 1) {
                float o = __shfl_up(incl, off, 64);
                if (t >= off) incl += o;
            }
            float ex = __shfl_up(incl, 1, 64);
            if (t == 0) ex = 0.f;
            float run = ex;
            #pragma unroll
            for (int j = 0; j < 8; ++j) { dst[t * 8 + j] = run; run += v[j]; }
        }
        return;
    }
    int b = (blk - 8) >> 3, cgx = (blk - 8) & 7;
    int cl = t & 15, seg = t >> 4;
    int c = cgx * 16 + cl;
    __shared__ float tots[16][17];
    const float* src = S_wx + (size_t)b * 512 * DCH + c;
    float* dst = sS_wx + (size_t)b * 512 * DCH + c;
    int s0 = seg * 32;
    float tot = 0.f;
    for (int j = 0; j < 32; ++j) tot += src[(size_t)(s0 + j) * DCH];
    tots[seg][cl] = tot;
    __syncthreads();
    if (t < 16) {
        float run = 0.f;
        for (int s = 0; s < 16; ++s) { float tmp = tots[s][t]; tots[s][t] = run; run += tmp; }
    }
    __syncthreads();
    float run = tots[seg][cl];
    for (int j = 0; j < 32; ++j) {
        float val = src[(size_t)(s0 + j) * DCH];
        dst[(size_t)(s0 + j) * DCH] = run;
        run += val;
    }
}

// ---------------- merged init: zero halo rows of P + weight repack W3 ----------------
__global__ __launch_bounds__(256) void k_init(const float* __restrict__ conv_w,
                                              unsigned short* __restrict__ W3,
                                              unsigned short* __restrict__ P) {
    int n = blockIdx.x, t = threadIdx.x;
    for (int i = t; i < 1024; i += 256) {
        int rr = i >> 7;                       // 0..7
        int row = (rr < 2) ? rr : 512 + rr;    // rows 0,1,514..519
        P[(n * PH + row) * DCH + (i & 127)] = 0;
    }
    int idx = n * 256 + t;                     // blocks 0..383 cover 98304 elems
    if (idx < 98304) {
        int e  = idx & 7;
        int o  = (idx >> 3) & 127;
        int kc = (idx >> 10) & 3;
        int kt2 = idx >> 12;                   // 0..23 = kt*2+ks
        int kt = kt2 >> 1, ks = kt2 & 1;
        int i  = (kt & 1) * 64 + (ks * 4 + kc) * 8 + e;
        int kn = kt >> 1;
        W3[idx] = f2bf(conv_w[(o * 128 + i) * 6 + kn]);
    }
}

// ---------------- Stage 5: apply scan -> prefix_x, write bf16 padded P ----------------
__global__ __launch_bounds__(256) void k_apply(const float* __restrict__ x,
                                               const float* __restrict__ exg,
                                               const float* __restrict__ sS_w,
                                               const float* __restrict__ sS_wx,
                                               unsigned short* __restrict__ P) {
    int t = threadIdx.x, w = t >> 6, lane = t & 63;
    int s = blockIdx.x * 4 + w;                // sub-chunk id
    int b = s >> 9, sb = s & 511;
    __shared__ float e2[256];
    e2[t] = exg[(size_t)blockIdx.x * 256 + t]; // all 4 waves' w values
    float2 axx = *(const float2*)(sS_wx + (size_t)s * DCH + 2 * lane);
    float aex = sS_w[s];
    __syncthreads();
    const float* es = e2 + w * 64;
    int pib0 = sb * 64;
    int n = b * 64 + (pib0 >> 9);
    int row0 = (pib0 & 511) + 2;
    const float* xp = x + ((size_t)b * LSEQ + pib0) * DCH + 2 * lane;
    unsigned short* pp = P + ((size_t)n * PH + row0) * DCH + 2 * lane;
    for (int j = 0; j < 64; ++j) {
        float e = es[j];
        aex += e;
        float2 xv = *(const float2*)xp;
        axx.x += e * xv.x;
        axx.y += e * xv.y;
        float inv = __builtin_amdgcn_rcpf(aex);
        unsigned pk = ((unsigned)f2bf(axx.y * inv + xv.y) << 16) | f2bf(axx.x * inv + xv.x);
        *(unsigned*)pp = pk;
        xp += DCH;
        pp += DCH;
    }
}

// ---------------- Stage 6: conv as bf16 MFMA GEMM (128x128 tile, K=768) ----------------
// Panel staged ONCE (144 rows x 128 ch, 36 KB, one barrier); 12 K-steps barrier-free.
// v4 (this round): (a) s_setprio(1) around the MFMA cluster — barrier-free loop gives
// wave phase-diversity, the regime where setprio measured +4-7% (T5); (b) epilogue
// computes per-column fp32 max of (acc+bias) -> brpart[n][tile][128], replacing
// k_tail's 512-row convout max pass. BIT-EXACT: f2bf monotone => max(bf16(v)) =
// bf16(max v); max over partials commutes. Scratch = dead panel rows >=140 (staged
// for DMA uniformity, never read: max read row = 64+48+15+5 = 132).
__global__ __launch_bounds__(256) void k_conv(const unsigned short* __restrict__ P,
                                              const unsigned short* __restrict__ W3,
                                              const float* __restrict__ conv_b,
                                              unsigned short* __restrict__ convout,
                                              float* __restrict__ brpart) {
    int n = blockIdx.x >> 2;
    int h0 = (blockIdx.x & 3) * 128;
    __shared__ __align__(16) char panel[144 * 256];   // 36864 B; epilogue reuses first 34816 B
    int t = threadIdx.x;
    int wave = t >> 6, lane = t & 63;
    f32x4 acc[4][4] = {};
    const unsigned short* Pn = P + (size_t)n * PH * DCH;
    int wm = (wave >> 1) * 64, wn = (wave & 1) * 64;
    int kchunk = lane >> 4;                   // 0..3 (MFMA k-slice group)
    int bcol = wn + (lane & 15);              // B out-channel base (+ni*16)

    bf16x8 breg[2][8];

    auto loadB = [&](int kt, bf16x8* dstB) {
        #pragma unroll
        for (int ks = 0; ks < 2; ++ks)
            #pragma unroll
            for (int ni = 0; ni < 4; ++ni)
                dstB[ks * 4 + ni] = *(const bf16x8*)(
                    W3 + (size_t)((kt * 2 + ks) * 4 + kchunk) * 1024 + (bcol + ni * 16) * 8);
    };

    // ---- stage the full panel: 9 rounds x (4 waves x 64 lanes x 16 B) = 144 rows ----
    {
        int c = lane & 15;                    // physical 16B-chunk within row
        #pragma unroll
        for (int j = 0; j < 9; ++j) {
            int r = j * 16 + wave * 4 + (lane >> 4);    // LDS row 0..143
            int gr = h0 + r;                             // global padded row
            int grc = min(gr, PH - 1);                   // clamp: rows >519 unread
            int srcc = (c & 8) | ((c & 7) ^ (gr & 7));   // source-side swizzle
            async_copy16(Pn + (size_t)grc * DCH + srcc * 8,
                         panel + j * 4096 + wave * 1024 + lane * 16);
        }
    }
    loadB(0, breg[0]);
    __syncthreads();                           // drains vmcnt(0): panel + breg[0] ready

    // ---- 12 K-steps, NO barriers: pure ds_read + MFMA on the resident panel ----
    #pragma unroll
    for (int kt = 0; kt < 12; ++kt) {
        if (kt < 11) loadB(kt + 1, breg[(kt + 1) & 1]);   // prefetch next B from L2
        int kn = kt >> 1;
        int cb = (kt & 1) * 8;                 // chunk-half: channels 0..63 / 64..127
        #pragma unroll
        for (int ks = 0; ks < 2; ++ks) {
            bf16x8 af[4];
            #pragma unroll
            for (int mi = 0; mi < 4; ++mi) {
                int row = wm + mi * 16 + (lane & 15) + kn;          // panel row
                int phys = cb + ((ks * 4 + kchunk) ^ ((h0 + row) & 7));
                af[mi] = *(const bf16x8*)(panel + row * 256 + phys * 16);
            }
            __builtin_amdgcn_s_setprio(1);
            #pragma unroll
            for (int mi = 0; mi < 4; ++mi)
                #pragma unroll
                for (int ni = 0; ni < 4; ++ni)
                    acc[mi][ni] = __builtin_amdgcn_mfma_f32_16x16x32_bf16(af[mi],
                                                                          breg[kt & 1][ks * 4 + ni],
                                                                          acc[mi][ni], 0, 0, 0);
            __builtin_amdgcn_s_setprio(0);
        }
    }

    // ---- per-column max partials (into dead panel rows 140..143, 1 KB) ----
    float* part = (float*)(panel + 35840);     // 256 floats: [wave][64 cols]
    {
        #pragma unroll
        for (int ni = 0; ni < 4; ++ni) {
            float pm = -INFINITY;
            #pragma unroll
            for (int mi = 0; mi < 4; ++mi)
                #pragma unroll
                for (int r = 0; r < 4; ++r) pm = fmaxf(pm, acc[mi][ni][r]);
            pm = fmaxf(pm, __shfl_xor(pm, 16, 64));
            pm = fmaxf(pm, __shfl_xor(pm, 32, 64));
            if (lane < 16) part[wave * 64 + ni * 16 + lane] = pm;
        }
    }
    __syncthreads();   // all panel reads complete + part published
    // reduce 2 wave-partials per column, add bias, store fp32 brpart
    if (t < 128) {
        int c = t;
        int w0 = c >> 6;                       // waves {w0, w0+2} cover column c
        float pm2 = fmaxf(part[w0 * 64 + (c & 63)], part[(w0 + 2) * 64 + (c & 63)]);
        brpart[((size_t)n * 4 + (blockIdx.x & 3)) * DCH + c] = pm2 + conv_b[c];
    }
    // C/D layout: col=lane&15, row=(lane>>4)*4+reg  [m89-verified]
    unsigned short* clds = (unsigned short*)panel;
    #pragma unroll
    for (int mi = 0; mi < 4; ++mi)
        #pragma unroll
        for (int ni = 0; ni < 4; ++ni) {
            int col = wn + ni * 16 + (lane & 15);
            float bias = conv_b[col];
            #pragma unroll
            for (int r = 0; r < 4; ++r) {
                int row = wm + mi * 16 + (lane >> 4) * 4 + r;
                clds[row * 136 + col] = f2bf(acc[mi][ni][r] + bias);
            }
        }
    __syncthreads();
    // coalesced store: 2048 granules of 16 B
    size_t base = (size_t)(n * 512 + h0) * DCH;
    #pragma unroll
    for (int it = 0; it < 8; ++it) {
        int idx = it * 256 + t;
        int row = idx >> 4, g = idx & 15;
        uint4 v = *(const uint4*)(clds + row * 136 + g * 8);
        *(uint4*)(convout + base + (size_t)row * DCH + g * 8) = v;
    }
}

// ---------------- Stage 7-9 fused tail: block_repr + a_s + a_o + fusion ----------------
// v2 (this round): phase A0 (512-row convout max pass) replaced by a 4-float max
// over k_conv's brpart partials (bit-exact; see k_conv) — one fewer convout HBM
// pass and ~3 fewer barriers per block.
__global__ __launch_bounds__(256) void k_tail(const unsigned short* __restrict__ conv,
                                              const unsigned short* __restrict__ P,
                                              const float* __restrict__ brpart,
                                              const float* __restrict__ fusion_w,
                                              const float* __restrict__ fusion_b,
                                              float* __restrict__ block_repr,
                                              float* __restrict__ out) {
    int n = blockIdx.x, t = threadIdx.x;
    int g = t & 15, rs = t >> 4;
    int b = n >> 6, c = n & 63;
    __shared__ __align__(16) float sp[512 * 17];   // partials / rp[16][130] / red / fu / comb
    __shared__ float s[512];
    __shared__ float br[128];
    __shared__ float as_l[128];
    __shared__ float ao_l[128];
    __shared__ float red[128];
    __shared__ int rb[128];
    float* rp = sp;                                 // [16][130] view
    const unsigned short* base = conv + (size_t)n * 512 * DCH;

    // ================= phase A: block_repr (from brpart) + a_s =================
    if (t < 128) {
        const float* bp = brpart + (size_t)n * 4 * DCH + t;
        float bm = fmaxf(fmaxf(bp[0], bp[DCH]), fmaxf(bp[2 * DCH], bp[3 * DCH]));
        float bmv = bf2f(f2bf(bm));            // round-trip matches old bf16-max semantics
        br[t] = bmv;
        block_repr[n * DCH + t] = bmv;
    }
    __syncthreads();

    float brv[8];
    #pragma unroll
    for (int e = 0; e < 8; ++e) brv[e] = br[g * 8 + e];
    for (int i = 0; i < 32; ++i) {
        int row = i * 16 + rs;
        uint4 v = *(const uint4*)(base + row * DCH + g * 8);
        unsigned vv[4] = {v.x, v.y, v.z, v.w};
        float p = 0.f;
        #pragma unroll
        for (int e = 0; e < 4; ++e) {
            p += bf2f((unsigned short)(vv[e] & 0xffff)) * brv[2 * e];
            p += bf2f((unsigned short)(vv[e] >> 16))    * brv[2 * e + 1];
        }
        sp[row * 17 + g] = p;
    }
    __syncthreads();
    #pragma unroll
    for (int rr = 0; rr < 2; ++rr) {
        int row = t * 2 + rr;
        float p = 0.f;
        #pragma unroll
        for (int j = 0; j < 16; ++j) p += sp[row * 17 + j];
        s[row] = p * SCALE_F;
    }
    __syncthreads();

    float* redA = sp;
    float mm = fmaxf(s[t], s[t + 256]);
    __syncthreads();          // all score reads of sp done before overwrite
    redA[t] = mm;
    __syncthreads();
    for (int off = 128; off > 0; off >>= 1) {
        if (t < off) redA[t] = fmaxf(redA[t], redA[t + off]);
        __syncthreads();
    }
    float smax = redA[0];
    __syncthreads();
    float e0 = expf(s[t] - smax), e1 = expf(s[t + 256] - smax);
    redA[t] = e0 + e1;
    __syncthreads();
    for (int off = 128; off > 0; off >>= 1) {
        if (t < off) redA[t] += redA[t + off];
        __syncthreads();
    }
    float inv = 1.f / redA[0];
    __syncthreads();
    s[t] = e0 * inv;
    s[t + 256] = e1 * inv;
    __syncthreads();

    float acc[8];
    #pragma unroll
    for (int e = 0; e < 8; ++e) acc[e] = 0.f;
    for (int i = 0; i < 32; ++i) {
        int row = i * 16 + rs;
        float w = s[row];
        uint4 v = *(const uint4*)(base + row * DCH + g * 8);
        unsigned vv[4] = {v.x, v.y, v.z, v.w};
        #pragma unroll
        for (int e = 0; e < 4; ++e) {
            acc[2 * e]     += w * bf2f((unsigned short)(vv[e] & 0xffff));
            acc[2 * e + 1] += w * bf2f((unsigned short)(vv[e] >> 16));
        }
    }
    #pragma unroll
    for (int e = 0; e < 8; ++e) rp[rs * 130 + g * 8 + e] = acc[e];
    __syncthreads();
    if (t < 128) {
        float p = 0.f;
        #pragma unroll
        for (int r2 = 0; r2 < 16; ++r2) p += rp[r2 * 130 + t];
        as_l[t] = p;
    }

    // ================= phase B: a_o = attn(br, xbo, xbo) (from P) =================
    if (t < 128) {
        int pib = (c + 1) * 512 - 64 + t;
        pib = min(pib, LSEQ - 1);
        int n2 = b * 64 + (pib >> 9);
        int row = (pib & 511) + 2;
        rb[t] = (n2 * PH + row) * DCH;
    }
    __syncthreads();
    #pragma unroll
    for (int r = 0; r < 8; ++r) {
        int row = rs * 8 + r;
        uint4 v = *(const uint4*)(P + rb[row] + g * 8);
        unsigned vv[4] = {v.x, v.y, v.z, v.w};
        float p = 0.f;
        #pragma unroll
        for (int e = 0; e < 4; ++e) {
            p += bf2f((unsigned short)(vv[e] & 0xffff)) * brv[2 * e];
            p += bf2f((unsigned short)(vv[e] >> 16))    * brv[2 * e + 1];
        }
        sp[row * 17 + g] = p;
    }
    __syncthreads();
    if (t < 128) {
        float p = 0.f;
        #pragma unroll
        for (int j = 0; j < 16; ++j) p += sp[t * 17 + j];
        s[t] = p * SCALE_F;
        red[t] = s[t];
    }
    __syncthreads();
    for (int off = 64; off > 0; off >>= 1) {
        if (t < off) red[t] = fmaxf(red[t], red[t + off]);
        __syncthreads();
    }
    float smaxB = red[0];
    __syncthreads();
    if (t < 128) {
        float e = expf(s[t] - smaxB);
        s[t] = e;
        red[t] = e;
    }
    __syncthreads();
    for (int off = 64; off > 0; off >>= 1) {
        if (t < off) red[t] += red[t + off];
        __syncthreads();
    }
    float invB = 1.f / red[0];
    __syncthreads();
    if (t < 128) s[t] *= invB;
    __syncthreads();
    float accB[8];
    #pragma unroll
    for (int e = 0; e < 8; ++e) accB[e] = 0.f;
    #pragma unroll
    for (int r = 0; r < 8; ++r) {
        int row = rs * 8 + r;
        float w = s[row];
        uint4 v = *(const uint4*)(P + rb[row] + g * 8);
        unsigned vv[4] = {v.x, v.y, v.z, v.w};
        #pragma unroll
        for (int e = 0; e < 4; ++e) {
            accB[2 * e]     += w * bf2f((unsigned short)(vv[e] & 0xffff));
            accB[2 * e + 1] += w * bf2f((unsigned short)(vv[e] >> 16));
        }
    }
    #pragma unroll
    for (int e = 0; e < 8; ++e) sp[rs * 130 + g * 8 + e] = accB[e];
    __syncthreads();
    if (t < 128) {
        float p = 0.f;
        #pragma unroll
        for (int r2 = 0; r2 < 16; ++r2) p += sp[r2 * 130 + t];
        ao_l[t] = p;
    }
    __syncthreads();

    // ================= phase C: out = concat(a_s,a_o,br) @ fusion_w + b =================
    float* fu = sp + 8320;
    if (t < 128) {
        fu[t] = as_l[t];
        fu[128 + t] = ao_l[t];
        fu[256 + t] = br[t];
    }
    __syncthreads();
    {
        int col = t & 127, h = t >> 7;
        float a2 = (h == 0) ? fusion_b[col] : 0.f;
        for (int j = h * 192; j < h * 192 + 192; ++j)
            a2 += fu[j] * fusion_w[j * DCH + col];
        sp[h * 128 + col] = a2;
    }
    __syncthreads();
    if (t < 128) {
        float v = sp[t] + sp[128 + t];
        out[n * DCH + t] = v;
        out[NB * 64 * DCH + n * DCH + t] = v;
    }
}

extern "C" void kernel_launch(void* const* d_in, const int* in_sizes, int n_in,
                              void* d_out, int out_size, void* d_ws, size_t ws_size,
                              hipStream_t stream) {
    const float* x        = (const float*)d_in[0];
    const float* w_lw     = (const float*)d_in[1];
    const float* b_lw     = (const float*)d_in[2];
    const float* conv_w   = (const float*)d_in[3];
    const float* conv_b   = (const float*)d_in[4];
    const float* fusion_w = (const float*)d_in[5];
    const float* fusion_b = (const float*)d_in[6];
    float* out = (float*)d_out;

    char* ws = (char*)d_ws;
    size_t off = 0;
    auto alloc = [&](size_t bytes) { char* p = ws + off; off += (bytes + 255) & ~(size_t)255; return p; };
    float* logits     = (float*)alloc(NB * LSEQ * 4);
    float* exg        = (float*)alloc(NB * LSEQ * 4);
    float* subM       = (float*)alloc(NSUB * 4);
    float* seedM      = (float*)alloc(NSUB * 4);
    float* S_w        = (float*)alloc(NSUB * 4);
    float* sS_w       = (float*)alloc(NSUB * 4);
    float* S_wx       = (float*)alloc((size_t)NSUB * DCH * 4);
    float* sS_wx      = (float*)alloc((size_t)NSUB * DCH * 4);
    float* block_repr = (float*)alloc(NBLK * DCH * 4);
    float* brpart     = (float*)alloc((size_t)NBLK * 4 * DCH * 4);
    unsigned short* W3      = (unsigned short*)alloc(128 * 768 * 2);
    unsigned short* P       = (unsigned short*)alloc((size_t)NBLK * PH * DCH * 2);
    unsigned short* convout = (unsigned short*)alloc((size_t)NBLK * 512 * DCH * 2);

    k_init<<<NBLK, 256, 0, stream>>>(conv_w, W3, P);
    k_logits2<<<NCHUNK, 256, 0, stream>>>(x, w_lw, b_lw, logits, subM);
    k_seed_max2<<<NB, 64, 0, stream>>>(subM, seedM);
    k_sums<<<NCHUNK, 256, 0, stream>>>(x, logits, seedM, exg, S_w, S_wx);
    k_seed_both<<<72, 256, 0, stream>>>(S_w, sS_w, S_wx, sS_wx);
    k_apply<<<NSUB / 4, 256, 0, stream>>>(x, exg, sS_w, sS_wx, P);
    k_conv<<<NBLK * 4, 256, 0, stream>>>(P, W3, conv_b, convout, brpart);
    k_tail<<<NBLK, 256, 0, stream>>>(convout, P, brpart, fusion_w, fusion_b, block_repr, out);
}